// Round 12
// baseline (1336.773 us; speedup 1.0000x reference)
//
#include <hip/hip_runtime.h>
#include <hip/hip_bf16.h>

#define Ecnt 120000
#define Ncnt 15000
#define Tcnt 500000
#define NT256 ((Tcnt + 255) / 256)    // 1954 triplet tiles

typedef __attribute__((ext_vector_type(8))) short short8;
typedef __attribute__((ext_vector_type(4))) float floatx4;

__device__ __forceinline__ floatx4 mfma16(short8 a, short8 b, floatx4 c) {
    return __builtin_amdgcn_mfma_f32_16x16x32_bf16(a, b, c, 0, 0, 0);
}

__device__ __forceinline__ short f2bf(float f) {
    __hip_bfloat16 b = __float2bfloat16(f);
    short s;
    __builtin_memcpy(&s, &b, 2);
    return s;
}

__device__ __forceinline__ float bf2f(short s) {
    unsigned u = ((unsigned)(unsigned short)s) << 16;
    float f;
    __builtin_memcpy(&f, &u, 4);
    return f;
}

__device__ __forceinline__ unsigned pack2(float x, float y) {
    return (unsigned)(unsigned short)f2bf(x) | ((unsigned)(unsigned short)f2bf(y) << 16);
}

// bf16 MFMA tile swizzle: byte-col XOR (row&15)<<4, BOTH sides.
__device__ __forceinline__ int sidx(int row, int bc) {
    return row * 128 + (((bc) ^ ((row & 15) << 4)) >> 1);
}
__device__ __forceinline__ int sidxg(int row, int bc, int ldshorts) {
    return row * ldshorts + (((bc) ^ ((row & 15) << 4)) >> 1);
}

__device__ __forceinline__ void stage64x128(const float* __restrict__ src, size_t row0,
                                            short* __restrict__ lds, int tid) {
    #pragma unroll
    for (int it = 0; it < 8; ++it) {
        int chunk = tid + it * 256;
        int r = chunk >> 5, c4 = chunk & 31;
        float4 v = *(const float4*)&src[(row0 + r) * 128 + c4 * 4];
        *(uint2*)&lds[sidx(r, c4 * 8)] = make_uint2(pack2(v.x, v.y), pack2(v.z, v.w));
    }
}

__device__ __forceinline__ void stage_bf(const short* __restrict__ src, size_t row0,
                                         short* __restrict__ lds, int tid) {
    #pragma unroll
    for (int it = 0; it < 4; ++it) {
        int chunk = tid + it * 256;
        int r = chunk >> 4, cg = chunk & 15;
        uint4 v = *(const uint4*)&src[(row0 + r) * 128 + cg * 8];
        *(uint4*)&lds[sidx(r, cg * 16)] = v;
    }
}

// global-weight 8-col GEMM with 2-deep prefetch
template<int NKB, int K>
__device__ __forceinline__ void colmm8_pf(const short8 a[NKB], const short* __restrict__ wcol,
                                          floatx4 out[8]) {
    short8 w[2][NKB];
    #pragma unroll
    for (int kb = 0; kb < NKB; ++kb) w[0][kb] = *(const short8*)(wcol + kb * 32);
    #pragma unroll
    for (int kb = 0; kb < NKB; ++kb) w[1][kb] = *(const short8*)(wcol + 16 * K + kb * 32);
    #pragma unroll
    for (int c = 0; c < 8; ++c) {
        floatx4 acc = {0.f, 0.f, 0.f, 0.f};
        #pragma unroll
        for (int kb = 0; kb < NKB; ++kb) acc = mfma16(a[kb], w[c & 1][kb], acc);
        out[c] = acc;
        if (c + 2 < 8) {
            #pragma unroll
            for (int kb = 0; kb < NKB; ++kb)
                w[c & 1][kb] = *(const short8*)(wcol + (size_t)(c + 2) * 16 * K + kb * 32);
        }
    }
}

// LDS fragment-major 8-col GEMM
template<int NKB>
__device__ __forceinline__ void colmm8_lds(const short8 a[NKB], const short* __restrict__ wf,
                                           floatx4 out[8]) {
    short8 w[2][NKB];
    #pragma unroll
    for (int kb = 0; kb < NKB; ++kb) w[0][kb] = *(const short8*)(wf + kb * 512);
    #pragma unroll
    for (int kb = 0; kb < NKB; ++kb) w[1][kb] = *(const short8*)(wf + (NKB + kb) * 512);
    #pragma unroll
    for (int c = 0; c < 8; ++c) {
        floatx4 acc = {0.f, 0.f, 0.f, 0.f};
        #pragma unroll
        for (int kb = 0; kb < NKB; ++kb) acc = mfma16(a[kb], w[c & 1][kb], acc);
        out[c] = acc;
        if (c + 2 < 8) {
            #pragma unroll
            for (int kb = 0; kb < NKB; ++kb)
                w[c & 1][kb] = *(const short8*)(wf + ((c + 2) * NKB + kb) * 512);
        }
    }
}

// ---------------- small kernels ----------------

__launch_bounds__(256)
__global__ void sentinel_k(float* o, float v) { o[0] = v; }

__launch_bounds__(256)
__global__ void atype_k(const float* __restrict__ af, int* __restrict__ atype) {
    int n = blockIdx.x * 256 + threadIdx.x;
    if (n >= Ncnt) return;
    const float* r = af + (size_t)n * 133;
    int best = 0; float bv = r[0];
    for (int k = 1; k < 100; ++k) { float v = r[k]; if (v > bv) { bv = v; best = k; } }
    atype[n] = best;
}

__launch_bounds__(128)
__global__ void pemb_k(const float* __restrict__ emb, const float* __restrict__ W,
                       float* __restrict__ P1, float* __restrict__ P2) {
    int r = blockIdx.x, c = threadIdx.x;
    __shared__ float er[128];
    er[c] = emb[r * 128 + c];
    __syncthreads();
    float a1 = 0.f, a2 = 0.f;
    for (int k = 0; k < 128; ++k) {
        float e = er[k];
        a1 = fmaf(e, W[k * 128 + c], a1);
        a2 = fmaf(e, W[(128 + k) * 128 + c], a2);
    }
    P1[r * 128 + c] = a1;
    P2[r * 128 + c] = a2;
}

__launch_bounds__(256)
__global__ void rbf0_k(const float* __restrict__ dist, const float* __restrict__ freq,
                       float* __restrict__ rbf0) {
    int e = blockIdx.x * 256 + threadIdx.x;
    if (e >= Ecnt) return;
    float x = dist[e] * 0.125f;
    float x2 = x * x;
    float x5 = x2 * x2 * x;
    float env = 1.f / x - 28.f * x5 + 48.f * x5 * x - 21.f * x5 * x2;
    if (!(x < 1.f)) env = 0.f;
    #pragma unroll
    for (int r = 0; r < 16; ++r)
        rbf0[(size_t)e * 16 + r] = env * sinf(freq[r] * x);
}

__launch_bounds__(256)
__global__ void rbfh_k(const float* __restrict__ rbf0, const float* __restrict__ W,
                       const float* __restrict__ bias, float* __restrict__ Y) {
    int gid = blockIdx.x * 256 + threadIdx.x;
    int e = gid >> 7, c = gid & 127;
    float acc = bias[c];
    #pragma unroll
    for (int k = 0; k < 16; ++k)
        acc = fmaf(rbf0[(size_t)e * 16 + k], W[k * 128 + c], acc);
    Y[(size_t)e * 128 + c] = fmaxf(acc, 0.f);
}

__launch_bounds__(256)
__global__ void scatatom_k(const float* __restrict__ msg, const int* __restrict__ eid,
                           const int* __restrict__ aid, float* __restrict__ am) {
    int gid = blockIdx.x * 256 + threadIdx.x;
    int e = gid >> 7, c = gid & 127;
    float v = msg[(size_t)eid[e] * 128 + c];
    atomicAdd(&am[(size_t)aid[e] * 128 + c], v);
}

// ---------------- sorting (CSR by target edge) ----------------

__launch_bounds__(256)
__global__ void hist_k(const int* __restrict__ idx, int* __restrict__ cnt) {
    int t = blockIdx.x * 256 + threadIdx.x;
    if (t < Tcnt) atomicAdd(&cnt[idx[t]], 1);
}

__launch_bounds__(256)
__global__ void scan1_k(int* __restrict__ cnt, int* __restrict__ btot) {
    __shared__ int s[256];
    int t = threadIdx.x, i = blockIdx.x * 256 + t;
    int v = (i < Ecnt) ? cnt[i] : 0;
    s[t] = v;
    #pragma unroll
    for (int off = 1; off < 256; off <<= 1) {
        __syncthreads();
        int nv = (t >= off) ? s[t - off] + s[t] : s[t];
        __syncthreads();
        s[t] = nv;
    }
    if (i < Ecnt) cnt[i] = s[t] - v;
    if (t == 255) btot[blockIdx.x] = s[255];
}

__launch_bounds__(512)
__global__ void scan2_k(const int* __restrict__ btot, int* __restrict__ boff, int nb) {
    __shared__ int s[512];
    int t = threadIdx.x;
    int v = (t < nb) ? btot[t] : 0;
    s[t] = v;
    #pragma unroll
    for (int off = 1; off < 512; off <<= 1) {
        __syncthreads();
        int nv = (t >= off) ? s[t - off] + s[t] : s[t];
        __syncthreads();
        s[t] = nv;
    }
    if (t < nb) boff[t] = s[t] - v;
}

__launch_bounds__(256)
__global__ void scan3_k(const int* __restrict__ basep, const int* __restrict__ boff,
                        int* __restrict__ sstart, int* __restrict__ cur) {
    int i = blockIdx.x * 256 + threadIdx.x;
    if (i < Ecnt) {
        int v = basep[i] + boff[i >> 8];
        sstart[i] = v;
        cur[i] = v;
    }
    if (i == 0) sstart[Ecnt] = Tcnt;
}

__launch_bounds__(256)
__global__ void perm_k(const int* __restrict__ idx, const float* __restrict__ angle,
                       int* __restrict__ cur, int* __restrict__ eids,
                       float* __restrict__ angs) {
    int t = blockIdx.x * 256 + threadIdx.x;
    if (t >= Tcnt) return;
    int e = idx[t];
    int p = atomicAdd(&cur[e], 1);
    eids[p] = e;
    angs[p] = angle[t];
}

// ---------------- weight conversion (batched) ----------------

// 11 matrices [col][K] (K=128), optional sigma-permuted K index
struct WPack {
    const float* src[11];
    short* dst[11];
    int perm[11];
};
__launch_bounds__(256)
__global__ void transmany_k(WPack p) {
    int m = blockIdx.x >> 6;                          // 64 blocks per matrix
    int i = ((blockIdx.x & 63) << 8) + threadIdx.x;   // 0..16383
    int c = i & 127, pi = i >> 7;
    int k = p.perm[m] ? ((pi & 7) * 16 + (pi >> 3)) : pi;
    p.dst[m][c * 128 + pi] = f2bf(p.src[m][(size_t)k * 128 + c]);
}

// 6 matrices fragment-major: out[((c*NKB+kb)*64+lane)*8+e]
struct FPack {
    const float* src[6];
    short* dst[6];
    int nkb[6];
};
__launch_bounds__(256)
__global__ void transfragall_k(FPack p) {
    int m = blockIdx.x >> 6;
    int i = ((blockIdx.x & 63) << 8) + threadIdx.x;
    int NKB = p.nkb[m];
    if (i >= NKB * 4096) return;
    int e = i & 7;
    int lane = (i >> 3) & 63;
    int ckb = i >> 9;
    int c = ckb / NKB, kb = ckb - c * NKB;
    int n = c * 16 + (lane & 15);
    int k = kb * 32 + (lane >> 4) * 8 + e;
    p.dst[m][i] = f2bf(p.src[m][(size_t)k * 128 + n]);
}

__launch_bounds__(256)
__global__ void transWi1_k(const float* __restrict__ W, short* __restrict__ out) {
    int i = blockIdx.x * 256 + threadIdx.x;
    if (i >= 128 * 160) return;
    int c = i / 160, k = i % 160;
    out[i] = (k < 147) ? f2bf(W[k * 128 + c]) : (short)0;
}

// ---------------- triplet: persistent, 1024 thr, 256-row tile, weights in LDS ----------------
// __launch_bounds__(1024, 4): 1024-thr block = 4 waves/EU exactly; the min-waves
// hint caps the allocator at 128 VGPR (instead of a 64-VGPR squeeze + spills, r11).
__launch_bounds__(1024, 4)
__global__ void triplet_mfma_k(const float* __restrict__ angs, const int* __restrict__ eids,
                               const float* __restrict__ rbf0,
                               const short* __restrict__ W1f, const short* __restrict__ W2f,
                               const short* __restrict__ W3f, const float* __restrict__ upB,
                               const short* __restrict__ xdown, short* __restrict__ ysort) {
    __shared__ short wl[77824];          // 152 KB
    short* w1  = wl;                     // 12288 (96x128 frag-major)
    short* w2  = wl + 12288;             // 16384
    short* w3  = wl + 28672;             // 16384
    short* dat = wl + 45056;             // 32768 (256-row swizzled tile)

    const int tid = threadIdx.x;
    const int lane = tid & 63;
    const int w = tid >> 6;               // 0..15
    const int kgrp = lane >> 4;
    const int ccol = lane & 15;
    const int arow = w * 16 + ccol;       // 0..255
    const int cr0  = w * 16 + kgrp * 4;

    for (int i = tid; i < 1536; i += 1024)
        *(uint4*)&w1[i * 8] = *(const uint4*)&W1f[i * 8];
    for (int i = tid; i < 2048; i += 1024)
        *(uint4*)&w2[i * 8] = *(const uint4*)&W2f[i * 8];
    for (int i = tid; i < 2048; i += 1024)
        *(uint4*)&w3[i * 8] = *(const uint4*)&W3f[i * 8];
    __syncthreads();

    float bu[8];
    #pragma unroll
    for (int c = 0; c < 8; ++c) bu[c] = upB[c * 16 + ccol];
    const short* wf1 = w1 + lane * 8;
    const short* wf2 = w2 + lane * 8;
    const short* wf3 = w3 + lane * 8;

    for (int tile = blockIdx.x; tile < NT256; tile += gridDim.x) {
        const int row0 = tile * 256;

        // wave-local sbf staging (band-local -> no barrier)
        {
            int srow = row0 + arow;
            float cb[6], rb[16];
            if (srow < Tcnt) {
                float ang = angs[srow];
                int ge = eids[srow];
                float c1 = cosf(ang);
                cb[0] = 1.f; cb[1] = c1;
                #pragma unroll
                for (int a = 2; a < 6; ++a) cb[a] = 2.f * c1 * cb[a - 1] - cb[a - 2];
                #pragma unroll
                for (int i4 = 0; i4 < 4; ++i4) {
                    float4 r4 = *(const float4*)&rbf0[(size_t)ge * 16 + i4 * 4];
                    rb[i4*4+0] = r4.x; rb[i4*4+1] = r4.y; rb[i4*4+2] = r4.z; rb[i4*4+3] = r4.w;
                }
            } else {
                #pragma unroll
                for (int a = 0; a < 6; ++a) cb[a] = 0.f;
                #pragma unroll
                for (int q = 0; q < 16; ++q) rb[q] = 0.f;
            }
            #pragma unroll
            for (int m = 0; m < 12; ++m) {
                int v0 = kgrp * 24 + 2 * m;
                *(unsigned*)&dat[sidx(arow, 2 * v0)] =
                    pack2(cb[v0 >> 4] * rb[v0 & 15], cb[(v0 + 1) >> 4] * rb[(v0 + 1) & 15]);
            }
        }

        int eidc[4];
        #pragma unroll
        for (int j = 0; j < 4; ++j) {
            int sr = row0 + cr0 + j;
            eidc[j] = (sr < Tcnt) ? eids[sr] : -1;
        }
        short8 xds[4];
        #pragma unroll
        for (int j = 0; j < 4; ++j) {
            if (eidc[j] >= 0)
                xds[j] = *(const short8*)&xdown[(size_t)eidc[j] * 128 + ccol * 8];
            else
                xds[j] = short8{0, 0, 0, 0, 0, 0, 0, 0};
        }

        floatx4 o[8];

        // GEMM1 K=96
        {
            short8 a3[3];
            #pragma unroll
            for (int kb = 0; kb < 3; ++kb)
                a3[kb] = *(const short8*)&dat[sidx(arow, kb * 64 + kgrp * 16)];
            colmm8_lds<3>(a3, wf1, o);
            #pragma unroll
            for (int c = 0; c < 8; ++c)
                #pragma unroll
                for (int j = 0; j < 4; ++j)
                    dat[sidx(cr0 + j, 2 * (c * 16 + ccol))] = f2bf(fmaxf(o[c][j], 0.f));
        }

        // GEMM2 K=128 (* xd)
        {
            short8 a4[4];
            #pragma unroll
            for (int kb = 0; kb < 4; ++kb)
                a4[kb] = *(const short8*)&dat[sidx(arow, kb * 64 + kgrp * 16)];
            colmm8_lds<4>(a4, wf2, o);
            #pragma unroll
            for (int c = 0; c < 8; ++c)
                #pragma unroll
                for (int j = 0; j < 4; ++j)
                    dat[sidx(cr0 + j, 2 * (c * 16 + ccol))] =
                        f2bf(fmaxf(o[c][j], 0.f) * bf2f(xds[j][c]));
        }

        // GEMM3 K=128 -> ysort
        {
            short8 a4[4];
            #pragma unroll
            for (int kb = 0; kb < 4; ++kb)
                a4[kb] = *(const short8*)&dat[sidx(arow, kb * 64 + kgrp * 16)];
            colmm8_lds<4>(a4, wf3, o);
            short8 y[4];
            #pragma unroll
            for (int c = 0; c < 8; ++c)
                #pragma unroll
                for (int j = 0; j < 4; ++j)
                    y[j][c] = f2bf(fmaxf(o[c][j] + bu[c], 0.f));
            #pragma unroll
            for (int j = 0; j < 4; ++j) {
                int row = row0 + cr0 + j;
                if (row < Tcnt)
                    *(short8*)&ysort[(size_t)row * 128 + ccol * 8] = y[j];
            }
        }
    }
}

// ---------------- fused layerB: CSR segment-sum + res-MLP + msg update (r10) ----------------
__launch_bounds__(256)
__global__ void layerBf_k(const short* __restrict__ ysort, const int* __restrict__ sstart,
                          const short* __restrict__ r1Wt, const float* __restrict__ r1B,
                          const short* __restrict__ r2Wt, const float* __restrict__ r2B,
                          float* __restrict__ msg) {
    __shared__ short ldsb[64 * 128];
    __shared__ float aggf[64 * 128];
    const int tid = threadIdx.x;
    const int lane = tid & 63, w = tid >> 6;
    const int row0 = blockIdx.x * 64;
    const int g16 = lane & 15;
    const int q   = lane >> 4;

    for (int it = 0; it < 16; ++it) {
        int el = it * 4 + w;
        int e = row0 + el;
        int s = sstart[e], tEnd = sstart[e + 1];
        float acc[8] = {0.f, 0.f, 0.f, 0.f, 0.f, 0.f, 0.f, 0.f};
        for (int r = s + q; r < tEnd; r += 4) {
            short8 y = *(const short8*)&ysort[(size_t)r * 128 + g16 * 8];
            #pragma unroll
            for (int c = 0; c < 8; ++c) acc[c] += bf2f(y[c]);
        }
        #pragma unroll
        for (int c = 0; c < 8; ++c) {
            acc[c] += __shfl_xor(acc[c], 16);
            acc[c] += __shfl_xor(acc[c], 32);
        }
        if (q == 0) {
            unsigned u[4];
            #pragma unroll
            for (int h = 0; h < 4; ++h) u[h] = pack2(acc[2 * h], acc[2 * h + 1]);
            *(uint4*)&ldsb[sidx(el, g16 * 16)] = make_uint4(u[0], u[1], u[2], u[3]);
            *(float4*)&aggf[el * 128 + g16 * 8]     = make_float4(acc[0], acc[1], acc[2], acc[3]);
            *(float4*)&aggf[el * 128 + g16 * 8 + 4] = make_float4(acc[4], acc[5], acc[6], acc[7]);
        }
    }
    __syncthreads();

    const int kgrp = lane >> 4, ccol = lane & 15;
    const int arow = w * 16 + ccol;
    const int cr0  = w * 16 + kgrp * 4;
    short8 a1[4];
    #pragma unroll
    for (int kb = 0; kb < 4; ++kb)
        a1[kb] = *(const short8*)&ldsb[sidx(arow, kb * 64 + kgrp * 16)];
    floatx4 o[8];
    colmm8_pf<4, 128>(a1, r1Wt + ccol * 128 + kgrp * 8, o);
    #pragma unroll
    for (int c = 0; c < 8; ++c) {
        int colg = c * 16 + ccol;
        float b1 = r1B[colg];
        #pragma unroll
        for (int j = 0; j < 4; ++j)
            ldsb[sidx(cr0 + j, 2 * colg)] = f2bf(fmaxf(o[c][j] + b1, 0.f));
    }
    short8 a2[4];
    #pragma unroll
    for (int kb = 0; kb < 4; ++kb)
        a2[kb] = *(const short8*)&ldsb[sidx(arow, kb * 64 + kgrp * 16)];
    colmm8_pf<4, 128>(a2, r2Wt + ccol * 128 + kgrp * 8, o);
    #pragma unroll
    for (int c = 0; c < 8; ++c) {
        int colg = c * 16 + ccol;
        float b2 = r2B[colg];
        #pragma unroll
        for (int j = 0; j < 4; ++j) {
            size_t ofs = (size_t)(row0 + cr0 + j) * 128 + colg;
            float ag = aggf[(cr0 + j) * 128 + ccol * 8 + c];
            msg[ofs] = msg[ofs] + ag + fmaxf(o[c][j] + b2, 0.f);
        }
    }
}

// ---------------- initial message (K=160, pad 147) ----------------
__launch_bounds__(256, 3)
__global__ void imsg_k(const float* __restrict__ af, const float* __restrict__ ef,
                       const int* __restrict__ idx_j,
                       const short* __restrict__ Wt, const float* __restrict__ bias,
                       float* __restrict__ msg) {
    __shared__ short lds[64 * 256];
    const int tid = threadIdx.x;
    const int lane = tid & 63, w = tid >> 6;
    const int row0 = blockIdx.x * 64;

    #pragma unroll
    for (int it = 0; it < 5; ++it) {
        int chunk = tid + it * 256;
        int r = chunk / 20, cg = chunk % 20;
        int row = row0 + r;
        int g = idx_j[row];
        unsigned u[4];
        #pragma unroll
        for (int h = 0; h < 4; ++h) {
            int k0 = cg * 8 + 2 * h;
            int k1 = k0 + 1;
            float f0 = (k0 < 133) ? af[(size_t)g * 133 + k0]
                     : (k0 < 147) ? ef[(size_t)row * 14 + (k0 - 133)] : 0.f;
            float f1 = (k1 < 133) ? af[(size_t)g * 133 + k1]
                     : (k1 < 147) ? ef[(size_t)row * 14 + (k1 - 133)] : 0.f;
            u[h] = pack2(f0, f1);
        }
        *(uint4*)&lds[sidxg(r, cg * 16, 256)] = make_uint4(u[0], u[1], u[2], u[3]);
    }
    __syncthreads();

    const int kgrp = lane >> 4, ccol = lane & 15;
    const int arow = w * 16 + ccol;
    const int cr0  = w * 16 + kgrp * 4;
    short8 a[5];
    #pragma unroll
    for (int kb = 0; kb < 5; ++kb)
        a[kb] = *(const short8*)&lds[sidxg(arow, kb * 64 + kgrp * 16, 256)];
    floatx4 o[8];
    colmm8_pf<5, 160>(a, Wt + ccol * 160 + kgrp * 8, o);
    #pragma unroll
    for (int c = 0; c < 8; ++c) {
        int colg = c * 16 + ccol;
        float bv = bias[colg];
        #pragma unroll
        for (int j = 0; j < 4; ++j)
            msg[(size_t)(row0 + cr0 + j) * 128 + colg] = fmaxf(o[c][j] + bv, 0.f);
    }
}

// ---------------- layerA (r10: streaming weights) ----------------
__launch_bounds__(256, 3)
__global__ void layerA_k(const float* __restrict__ msg, const short* __restrict__ rbfe,
                         const short* __restrict__ kjWt, const float* __restrict__ kjB,
                         const short* __restrict__ rbf2Wt, const float* __restrict__ rbf2B,
                         const short* __restrict__ downWt, const float* __restrict__ downB,
                         short* __restrict__ xdown) {
    __shared__ short ldsM[64 * 128];
    __shared__ short ldsR[64 * 128];
    const int tid = threadIdx.x;
    const int lane = tid & 63, w = tid >> 6;
    const size_t row0 = (size_t)blockIdx.x * 64;
    stage64x128(msg, row0, ldsM, tid);
    stage_bf(rbfe, row0, ldsR, tid);
    __syncthreads();
    const int kgrp = lane >> 4, ccol = lane & 15;
    const int arow = w * 16 + ccol;
    const int cr0  = w * 16 + kgrp * 4;
    short8 aM[4], aR[4];
    #pragma unroll
    for (int kb = 0; kb < 4; ++kb) {
        aM[kb] = *(const short8*)&ldsM[sidx(arow, kb * 64 + kgrp * 16)];
        aR[kb] = *(const short8*)&ldsR[sidx(arow, kb * 64 + kgrp * 16)];
    }
    floatx4 oR[8], oK[8];
    colmm8_pf<4, 128>(aR, rbf2Wt + ccol * 128 + kgrp * 8, oR);
    colmm8_pf<4, 128>(aM, kjWt   + ccol * 128 + kgrp * 8, oK);
    #pragma unroll
    for (int c = 0; c < 8; ++c) {
        int colg = c * 16 + ccol;
        float rb = rbf2B[colg], kbb = kjB[colg];
        #pragma unroll
        for (int j = 0; j < 4; ++j) {
            float x = fmaxf(oK[c][j] + kbb, 0.f) * fmaxf(oR[c][j] + rb, 0.f);
            ldsM[sidx(cr0 + j, 2 * colg)] = f2bf(x);
        }
    }
    short8 aX[4];
    #pragma unroll
    for (int kb = 0; kb < 4; ++kb)
        aX[kb] = *(const short8*)&ldsM[sidx(arow, kb * 64 + kgrp * 16)];
    colmm8_pf<4, 128>(aX, downWt + ccol * 128 + kgrp * 8, oK);
    #pragma unroll
    for (int j = 0; j < 4; ++j) {
        short8 v;
        #pragma unroll
        for (int c = 0; c < 8; ++c)
            v[c] = f2bf(fmaxf(oK[c][j] + downB[c * 16 + ccol], 0.f));
        *(short8*)&xdown[(row0 + cr0 + j) * 128 + ccol * 8] = v;
    }
}

// ---------------- rbfe (bf16 out) ----------------
__launch_bounds__(256, 3)
__global__ void rbfe_k(const float* __restrict__ rbfh, const short* __restrict__ W3t,
                       const float* __restrict__ bias,
                       const int* __restrict__ idx_i, const int* __restrict__ idx_j,
                       const int* __restrict__ atype,
                       const float* __restrict__ P1, const float* __restrict__ P2,
                       short* __restrict__ out) {
    __shared__ short lds[64 * 128];
    const int tid = threadIdx.x;
    const int lane = tid & 63, w = tid >> 6;
    const size_t row0 = (size_t)blockIdx.x * 64;
    stage64x128(rbfh, row0, lds, tid);
    const int kgrp = lane >> 4, ccol = lane & 15;
    const int arow = w * 16 + ccol;
    const int cr0  = w * 16 + kgrp * 4;
    const float* p1p[4]; const float* p2p[4];
    #pragma unroll
    for (int j = 0; j < 4; ++j) {
        size_t row = row0 + cr0 + j;
        p1p[j] = P1 + (size_t)atype[idx_i[row]] * 128;
        p2p[j] = P2 + (size_t)atype[idx_j[row]] * 128;
    }
    __syncthreads();
    short8 a[4];
    #pragma unroll
    for (int kb = 0; kb < 4; ++kb)
        a[kb] = *(const short8*)&lds[sidx(arow, kb * 64 + kgrp * 16)];
    floatx4 o[8];
    colmm8_pf<4, 128>(a, W3t + ccol * 128 + kgrp * 8, o);
    #pragma unroll
    for (int c = 0; c < 8; ++c) {
        int colg = c * 16 + ccol;
        float bv = bias[colg];
        #pragma unroll
        for (int j = 0; j < 4; ++j)
            out[(row0 + cr0 + j) * 128 + colg] =
                f2bf(fmaxf(o[c][j] + bv + p1p[j][colg] + p2p[j][colg], 0.f));
    }
}

// ---------------- concat GEMM (fp32, final projection only) ----------------
__launch_bounds__(256)
__global__ void concatgemm_k(const float* __restrict__ IN1, int K1,
                             const float* __restrict__ IN2, int K2,
                             const float* __restrict__ W, const float* __restrict__ bias,
                             float* __restrict__ Y, int M) {
    __shared__ float xs[96 * 68];
    const int tid = threadIdx.x;
    const int row0 = blockIdx.x * 64;
    const int col8 = (tid & 15) * 8;
    const int r0 = (tid >> 4) * 4;
    const int K = K1 + K2;

    float acc[4][8];
    #pragma unroll
    for (int r = 0; r < 4; ++r)
        #pragma unroll
        for (int c = 0; c < 8; ++c) acc[r][c] = 0.f;

    for (int kb = 0; kb < K; kb += 96) {
        int kc = (K - kb < 96) ? (K - kb) : 96;
        __syncthreads();
        for (int idx = tid; idx < 64 * 96; idx += 256) {
            int r = idx / 96, kl = idx % 96;
            if (kl < kc) {
                int row = row0 + r;
                float v = 0.f;
                if (row < M) {
                    int kg = kb + kl;
                    v = (kg < K1) ? IN1[(size_t)row * K1 + kg]
                                  : IN2[(size_t)row * K2 + (kg - K1)];
                }
                xs[kl * 68 + r] = v;
            }
        }
        __syncthreads();
        for (int k = 0; k < kc; ++k) {
            float4 xv = *(const float4*)&xs[(kb + k - kb) * 0 + k * 68 + r0];
            const float* wr = &W[(size_t)(kb + k) * 128 + col8];
            float4 w0 = *(const float4*)wr;
            float4 w1 = *(const float4*)(wr + 4);
            float xr[4] = {xv.x, xv.y, xv.z, xv.w};
            float wc[8] = {w0.x, w0.y, w0.z, w0.w, w1.x, w1.y, w1.z, w1.w};
            #pragma unroll
            for (int r = 0; r < 4; ++r)
                #pragma unroll
                for (int c = 0; c < 8; ++c)
                    acc[r][c] = fmaf(xr[r], wc[c], acc[r][c]);
        }
    }

    float4 b0 = *(const float4*)&bias[col8];
    float4 b1 = *(const float4*)&bias[col8 + 4];
    float bb[8] = {b0.x, b0.y, b0.z, b0.w, b1.x, b1.y, b1.z, b1.w};
    #pragma unroll
    for (int r = 0; r < 4; ++r) {
        int row = row0 + r0 + r;
        if (row >= M) continue;
        float v[8];
        #pragma unroll
        for (int c = 0; c < 8; ++c) v[c] = fmaxf(acc[r][c] + bb[c], 0.f);
        *(float4*)&Y[(size_t)row * 128 + col8]     = make_float4(v[0], v[1], v[2], v[3]);
        *(float4*)&Y[(size_t)row * 128 + col8 + 4] = make_float4(v[4], v[5], v[6], v[7]);
    }
}

// ---------------- host ----------------

extern "C" void kernel_launch(void* const* d_in, const int* in_sizes, int n_in,
                              void* d_out, int out_size, void* d_ws, size_t ws_size,
                              hipStream_t stream) {
    const float* atom_feature = (const float*)d_in[0];
    const float* edge_feature = (const float*)d_in[1];
    const float* dist         = (const float*)d_in[2];
    const float* angle        = (const float*)d_in[3];
    const float* W_i1_w       = (const float*)d_in[4];
    const float* W_i1_b       = (const float*)d_in[5];
    const float* emb_table    = (const float*)d_in[6];
    const float* lin_rbf_w    = (const float*)d_in[7];
    const float* lin_rbf_b    = (const float*)d_in[8];
    const float* lin_emb_w    = (const float*)d_in[9];
    const float* lin_emb_b    = (const float*)d_in[10];
    const float* bessel_freq  = (const float*)d_in[11];
    const float* L_rbf2_w     = (const float*)d_in[12];
    const float* L_rbf2_b     = (const float*)d_in[13];
    const float* L_kj_w       = (const float*)d_in[14];
    const float* L_kj_b       = (const float*)d_in[15];
    const float* L_sbf1_w     = (const float*)d_in[16];
    const float* L_sbf2_w     = (const float*)d_in[17];
    const float* L_down_w     = (const float*)d_in[18];
    const float* L_down_b     = (const float*)d_in[19];
    const float* L_up_w       = (const float*)d_in[20];
    const float* L_up_b       = (const float*)d_in[21];
    const float* L_res1_w     = (const float*)d_in[22];
    const float* L_res1_b     = (const float*)d_in[23];
    const float* L_res2_w     = (const float*)d_in[24];
    const float* L_res2_b     = (const float*)d_in[25];
    const float* W_o_w        = (const float*)d_in[26];
    const float* W_o_b        = (const float*)d_in[27];
    const int* idx_i          = (const int*)d_in[28];
    const int* idx_j          = (const int*)d_in[29];
    const int* idx_kj         = (const int*)d_in[30];
    const int* ib_eid         = (const int*)d_in[32];
    const int* ib_atom        = (const int*)d_in[33];

    float* ws = (float*)d_ws;
    size_t off = 0;
    auto take = [&](size_t n) { float* p = ws + off; off += n; return p; };
    float* msg   = take((size_t)Ecnt * 128);
    short* rbfe  = (short*)take((size_t)Ecnt * 64);
    short* sxd   = (short*)take((size_t)Ecnt * 64);
    short* ysort = (short*)take((size_t)Tcnt * 64);
    float* rbf0b = take((size_t)Ecnt * 16);
    float* P1    = take(100 * 128);
    float* P2    = take(100 * 128);
    int*   atyp  = (int*)take(Ncnt);
    int*   cnts  = (int*)take(Ecnt);
    int*   sstart= (int*)take(Ecnt + 1);
    int*   cur   = (int*)take(Ecnt);
    int*   btot  = (int*)take(512);
    int*   boff  = (int*)take(512);
    int*   eids  = (int*)take(Tcnt);
    float* angs  = take(Tcnt);
    short* wts   = (short*)take(160000);

    if (off * sizeof(float) > ws_size) {
        sentinel_k<<<1, 256, 0, stream>>>((float*)d_out, (float)ws_size);
        return;
    }

    float* rbfh_s = (float*)ysort;
    float* atomm  = (float*)ysort;

    const int GE  = Ecnt / 64;
    const int GN  = (Ncnt + 63) / 64;
    const int NBE = (Ecnt + 255) / 256;
    const int NBT = (Tcnt + 255) / 256;

    atype_k<<<(Ncnt + 255) / 256, 256, 0, stream>>>(atom_feature, atyp);
    pemb_k<<<100, 128, 0, stream>>>(emb_table, lin_emb_w, P1, P2);
    rbf0_k<<<NBE, 256, 0, stream>>>(dist, bessel_freq, rbf0b);

    hipMemsetAsync(cnts, 0, (size_t)Ecnt * sizeof(int), stream);
    hist_k<<<NBT, 256, 0, stream>>>(idx_kj, cnts);
    scan1_k<<<NBE, 256, 0, stream>>>(cnts, btot);
    scan2_k<<<1, 512, 0, stream>>>(btot, boff, NBE);
    scan3_k<<<NBE, 256, 0, stream>>>(cnts, boff, sstart, cur);
    perm_k<<<NBT, 256, 0, stream>>>(idx_kj, angle, cur, eids, angs);

    // --- weight prep ---
    short* p = wts;
    short* wt1[2]; short* wt2[2]; short* wt3[2];
    short* wkj[2]; short* wr2f[2]; short* wdn[2]; short* wr1[2]; short* wr2[2];
    for (int l = 0; l < 2; ++l) {
        wt1[l] = p; p += 96 * 128;
        wt2[l] = p; p += 128 * 128;
        wt3[l] = p; p += 128 * 128;
        wkj[l] = p; p += 128 * 128;
        wr2f[l] = p; p += 128 * 128;
        wdn[l] = p; p += 128 * 128;
        wr1[l] = p; p += 128 * 128;
        wr2[l] = p; p += 128 * 128;
    }
    short* wemb3 = p; p += 128 * 128;
    short* wi1t  = p; p += 128 * 160;

    // [col][K] matrices (layerA/layerBf/rbfe), res1 with sigma-permuted K
    WPack wp;
    int m = 0;
    for (int l = 0; l < 2; ++l) {
        wp.src[m] = L_kj_w   + (size_t)l * 128 * 128; wp.dst[m] = wkj[l];  wp.perm[m++] = 0;
        wp.src[m] = L_rbf2_w + (size_t)l * 128 * 128; wp.dst[m] = wr2f[l]; wp.perm[m++] = 0;
        wp.src[m] = L_down_w + (size_t)l * 128 * 128; wp.dst[m] = wdn[l];  wp.perm[m++] = 0;
        wp.src[m] = L_res1_w + (size_t)l * 128 * 128; wp.dst[m] = wr1[l];  wp.perm[m++] = 1;
        wp.src[m] = L_res2_w + (size_t)l * 128 * 128; wp.dst[m] = wr2[l];  wp.perm[m++] = 0;
    }
    wp.src[m] = lin_emb_w + 256 * 128; wp.dst[m] = wemb3; wp.perm[m++] = 0;   // 11
    transmany_k<<<11 * 64, 256, 0, stream>>>(wp);

    // frag-major matrices (triplet)
    FPack fp;
    m = 0;
    for (int l = 0; l < 2; ++l) {
        fp.src[m] = L_sbf1_w + (size_t)l * 96 * 128;  fp.dst[m] = wt1[l]; fp.nkb[m++] = 3;
        fp.src[m] = L_sbf2_w + (size_t)l * 128 * 128; fp.dst[m] = wt2[l]; fp.nkb[m++] = 4;
        fp.src[m] = L_up_w   + (size_t)l * 128 * 128; fp.dst[m] = wt3[l]; fp.nkb[m++] = 4;
    }
    transfragall_k<<<6 * 64, 256, 0, stream>>>(fp);
    transWi1_k<<<(128 * 160 + 255) / 256, 256, 0, stream>>>(W_i1_w, wi1t);

    imsg_k<<<GE, 256, 0, stream>>>(atom_feature, edge_feature, idx_j, wi1t, W_i1_b, msg);
    rbfh_k<<<(Ecnt * 128) / 256, 256, 0, stream>>>(rbf0b, lin_rbf_w, lin_rbf_b, rbfh_s);
    rbfe_k<<<GE, 256, 0, stream>>>(rbfh_s, wemb3, lin_emb_b, idx_i, idx_j, atyp, P1, P2, rbfe);

    for (int l = 0; l < 2; ++l) {
        layerA_k<<<GE, 256, 0, stream>>>(msg, rbfe,
                                         wkj[l], L_kj_b + (size_t)l * 128,
                                         wr2f[l], L_rbf2_b + (size_t)l * 128,
                                         wdn[l], L_down_b + (size_t)l * 128, sxd);
        triplet_mfma_k<<<256, 1024, 0, stream>>>(angs, eids, rbf0b,
                                                 wt1[l], wt2[l], wt3[l],
                                                 L_up_b + (size_t)l * 128, sxd, ysort);
        layerBf_k<<<GE, 256, 0, stream>>>(ysort, sstart,
                                          wr1[l], L_res1_b + (size_t)l * 128,
                                          wr2[l], L_res2_b + (size_t)l * 128, msg);
    }

    hipMemsetAsync(atomm, 0, (size_t)Ncnt * 128 * sizeof(float), stream);
    scatatom_k<<<(Ecnt * 128) / 256, 256, 0, stream>>>(msg, ib_eid, ib_atom, atomm);
    concatgemm_k<<<GN, 256, 0, stream>>>(atom_feature, 133, atomm, 128,
                                         W_o_w, W_o_b, (float*)d_out, Ncnt);
}

// Round 13
// 1061.270 us; speedup vs baseline: 1.2596x; 1.2596x over previous
//
#include <hip/hip_runtime.h>
#include <hip/hip_bf16.h>

#define Ecnt 120000
#define Ncnt 15000
#define Tcnt 500000
#define NT128 ((Tcnt + 127) / 128)

typedef __attribute__((ext_vector_type(8))) short short8;
typedef __attribute__((ext_vector_type(4))) float floatx4;

__device__ __forceinline__ floatx4 mfma16(short8 a, short8 b, floatx4 c) {
    return __builtin_amdgcn_mfma_f32_16x16x32_bf16(a, b, c, 0, 0, 0);
}

__device__ __forceinline__ short f2bf(float f) {
    __hip_bfloat16 b = __float2bfloat16(f);
    short s;
    __builtin_memcpy(&s, &b, 2);
    return s;
}

__device__ __forceinline__ float bf2f(short s) {
    unsigned u = ((unsigned)(unsigned short)s) << 16;
    float f;
    __builtin_memcpy(&f, &u, 4);
    return f;
}

__device__ __forceinline__ unsigned pack2(float x, float y) {
    return (unsigned)(unsigned short)f2bf(x) | ((unsigned)(unsigned short)f2bf(y) << 16);
}

// bf16 MFMA tile swizzle: byte-col XOR (row&15)<<4, BOTH sides.
__device__ __forceinline__ int sidx(int row, int bc) {
    return row * 128 + (((bc) ^ ((row & 15) << 4)) >> 1);
}
__device__ __forceinline__ int sidxg(int row, int bc, int ldshorts) {
    return row * ldshorts + (((bc) ^ ((row & 15) << 4)) >> 1);
}

__device__ __forceinline__ void stage64x128(const float* __restrict__ src, size_t row0,
                                            short* __restrict__ lds, int tid) {
    #pragma unroll
    for (int it = 0; it < 8; ++it) {
        int chunk = tid + it * 256;
        int r = chunk >> 5, c4 = chunk & 31;
        float4 v = *(const float4*)&src[(row0 + r) * 128 + c4 * 4];
        *(uint2*)&lds[sidx(r, c4 * 8)] = make_uint2(pack2(v.x, v.y), pack2(v.z, v.w));
    }
}

__device__ __forceinline__ void stage_bf(const short* __restrict__ src, size_t row0,
                                         short* __restrict__ lds, int tid) {
    #pragma unroll
    for (int it = 0; it < 4; ++it) {
        int chunk = tid + it * 256;
        int r = chunk >> 4, cg = chunk & 15;
        uint4 v = *(const uint4*)&src[(row0 + r) * 128 + cg * 8];
        *(uint4*)&lds[sidx(r, cg * 16)] = v;
    }
}

// global-weight 8-col GEMM with 2-deep prefetch
template<int NKB, int K>
__device__ __forceinline__ void colmm8_pf(const short8 a[NKB], const short* __restrict__ wcol,
                                          floatx4 out[8]) {
    short8 w[2][NKB];
    #pragma unroll
    for (int kb = 0; kb < NKB; ++kb) w[0][kb] = *(const short8*)(wcol + kb * 32);
    #pragma unroll
    for (int kb = 0; kb < NKB; ++kb) w[1][kb] = *(const short8*)(wcol + 16 * K + kb * 32);
    #pragma unroll
    for (int c = 0; c < 8; ++c) {
        floatx4 acc = {0.f, 0.f, 0.f, 0.f};
        #pragma unroll
        for (int kb = 0; kb < NKB; ++kb) acc = mfma16(a[kb], w[c & 1][kb], acc);
        out[c] = acc;
        if (c + 2 < 8) {
            #pragma unroll
            for (int kb = 0; kb < NKB; ++kb)
                w[c & 1][kb] = *(const short8*)(wcol + (size_t)(c + 2) * 16 * K + kb * 32);
        }
    }
}

// LDS fragment-major 8-col GEMM
template<int NKB>
__device__ __forceinline__ void colmm8_lds(const short8 a[NKB], const short* __restrict__ wf,
                                           floatx4 out[8]) {
    short8 w[2][NKB];
    #pragma unroll
    for (int kb = 0; kb < NKB; ++kb) w[0][kb] = *(const short8*)(wf + kb * 512);
    #pragma unroll
    for (int kb = 0; kb < NKB; ++kb) w[1][kb] = *(const short8*)(wf + (NKB + kb) * 512);
    #pragma unroll
    for (int c = 0; c < 8; ++c) {
        floatx4 acc = {0.f, 0.f, 0.f, 0.f};
        #pragma unroll
        for (int kb = 0; kb < NKB; ++kb) acc = mfma16(a[kb], w[c & 1][kb], acc);
        out[c] = acc;
        if (c + 2 < 8) {
            #pragma unroll
            for (int kb = 0; kb < NKB; ++kb)
                w[c & 1][kb] = *(const short8*)(wf + ((c + 2) * NKB + kb) * 512);
        }
    }
}

// ---------------- small kernels ----------------

__launch_bounds__(256)
__global__ void sentinel_k(float* o, float v) { o[0] = v; }

__launch_bounds__(256)
__global__ void atype_k(const float* __restrict__ af, int* __restrict__ atype) {
    int n = blockIdx.x * 256 + threadIdx.x;
    if (n >= Ncnt) return;
    const float* r = af + (size_t)n * 133;
    int best = 0; float bv = r[0];
    for (int k = 1; k < 100; ++k) { float v = r[k]; if (v > bv) { bv = v; best = k; } }
    atype[n] = best;
}

__launch_bounds__(128)
__global__ void pemb_k(const float* __restrict__ emb, const float* __restrict__ W,
                       float* __restrict__ P1, float* __restrict__ P2) {
    int r = blockIdx.x, c = threadIdx.x;
    __shared__ float er[128];
    er[c] = emb[r * 128 + c];
    __syncthreads();
    float a1 = 0.f, a2 = 0.f;
    for (int k = 0; k < 128; ++k) {
        float e = er[k];
        a1 = fmaf(e, W[k * 128 + c], a1);
        a2 = fmaf(e, W[(128 + k) * 128 + c], a2);
    }
    P1[r * 128 + c] = a1;
    P2[r * 128 + c] = a2;
}

__launch_bounds__(256)
__global__ void rbf0_k(const float* __restrict__ dist, const float* __restrict__ freq,
                       float* __restrict__ rbf0) {
    int e = blockIdx.x * 256 + threadIdx.x;
    if (e >= Ecnt) return;
    float x = dist[e] * 0.125f;
    float x2 = x * x;
    float x5 = x2 * x2 * x;
    float env = 1.f / x - 28.f * x5 + 48.f * x5 * x - 21.f * x5 * x2;
    if (!(x < 1.f)) env = 0.f;
    #pragma unroll
    for (int r = 0; r < 16; ++r)
        rbf0[(size_t)e * 16 + r] = env * sinf(freq[r] * x);
}

// atom-CSR segment sum: atomm[a][c] = sum over sorted incoming edges
__launch_bounds__(256)
__global__ void atomsum_k(const float* __restrict__ msg, const int* __restrict__ eidsA,
                          const int* __restrict__ sstartA, float* __restrict__ am) {
    int gid = blockIdx.x * 256 + threadIdx.x;
    int a = gid >> 7, c = gid & 127;
    int s = sstartA[a], e = sstartA[a + 1];
    float acc = 0.f;
    for (int r = s; r < e; ++r)
        acc += msg[(size_t)eidsA[r] * 128 + c];
    am[(size_t)a * 128 + c] = acc;
}

// ---------------- sorting (generic CSR) ----------------

__launch_bounds__(256)
__global__ void hist_k(const int* __restrict__ idx, int* __restrict__ cnt, int n) {
    int t = blockIdx.x * 256 + threadIdx.x;
    if (t < n) atomicAdd(&cnt[idx[t]], 1);
}

// in-place: cnt -> per-block exclusive scan; block totals to btot
__launch_bounds__(256)
__global__ void scan1_k(int* __restrict__ cnt, int* __restrict__ btot, int n) {
    __shared__ int s[256];
    int t = threadIdx.x, i = blockIdx.x * 256 + t;
    int v = (i < n) ? cnt[i] : 0;
    s[t] = v;
    #pragma unroll
    for (int off = 1; off < 256; off <<= 1) {
        __syncthreads();
        int nv = (t >= off) ? s[t - off] + s[t] : s[t];
        __syncthreads();
        s[t] = nv;
    }
    if (i < n) cnt[i] = s[t] - v;
    if (t == 255) btot[blockIdx.x] = s[255];
}

__launch_bounds__(512)
__global__ void scan2_k(const int* __restrict__ btot, int* __restrict__ boff, int nb) {
    __shared__ int s[512];
    int t = threadIdx.x;
    int v = (t < nb) ? btot[t] : 0;
    s[t] = v;
    #pragma unroll
    for (int off = 1; off < 512; off <<= 1) {
        __syncthreads();
        int nv = (t >= off) ? s[t - off] + s[t] : s[t];
        __syncthreads();
        s[t] = nv;
    }
    if (t < nb) boff[t] = s[t] - v;
}

__launch_bounds__(256)
__global__ void scan3_k(const int* __restrict__ basep, const int* __restrict__ boff,
                        int* __restrict__ sstart, int* __restrict__ cur, int n, int total) {
    int i = blockIdx.x * 256 + threadIdx.x;
    if (i < n) {
        int v = basep[i] + boff[i >> 8];
        sstart[i] = v;
        cur[i] = v;
    }
    if (i == 0) sstart[n] = total;
}

// triplet payload scatter (sorted by target edge)
__launch_bounds__(256)
__global__ void perm_k(const int* __restrict__ idx, const float* __restrict__ angle,
                       int* __restrict__ cur, int* __restrict__ eids,
                       float* __restrict__ angs) {
    int t = blockIdx.x * 256 + threadIdx.x;
    if (t >= Tcnt) return;
    int e = idx[t];
    int p = atomicAdd(&cur[e], 1);
    eids[p] = e;
    angs[p] = angle[t];
}

// atom payload scatter (sorted by atom)
__launch_bounds__(256)
__global__ void permA_k(const int* __restrict__ aid, const int* __restrict__ eid,
                        int* __restrict__ cur, int* __restrict__ eidsA) {
    int t = blockIdx.x * 256 + threadIdx.x;
    if (t >= Ecnt) return;
    int p = atomicAdd(&cur[aid[t]], 1);
    eidsA[p] = eid[t];
}

// ---------------- weight conversion (batched) ----------------

struct WPack {
    const float* src[11];
    short* dst[11];
    int perm[11];
};
__launch_bounds__(256)
__global__ void transmany_k(WPack p) {
    int m = blockIdx.x >> 6;
    int i = ((blockIdx.x & 63) << 8) + threadIdx.x;
    int c = i & 127, pi = i >> 7;
    int k = p.perm[m] ? ((pi & 7) * 16 + (pi >> 3)) : pi;
    p.dst[m][c * 128 + pi] = f2bf(p.src[m][(size_t)k * 128 + c]);
}

struct FPack {
    const float* src[6];
    short* dst[6];
    int nkb[6];
};
__launch_bounds__(256)
__global__ void transfragall_k(FPack p) {
    int m = blockIdx.x >> 6;
    int i = ((blockIdx.x & 63) << 8) + threadIdx.x;
    int NKB = p.nkb[m];
    if (i >= NKB * 4096) return;
    int e = i & 7;
    int lane = (i >> 3) & 63;
    int ckb = i >> 9;
    int c = ckb / NKB, kb = ckb - c * NKB;
    int n = c * 16 + (lane & 15);
    int k = kb * 32 + (lane >> 4) * 8 + e;
    p.dst[m][i] = f2bf(p.src[m][(size_t)k * 128 + n]);
}

__launch_bounds__(256)
__global__ void transWi1_k(const float* __restrict__ W, short* __restrict__ out) {
    int i = blockIdx.x * 256 + threadIdx.x;
    if (i >= 128 * 160) return;
    int c = i / 160, k = i % 160;
    out[i] = (k < 147) ? f2bf(W[k * 128 + c]) : (short)0;
}

// lin_rbf_w [16][128] -> [col][K=32] bf16, zero-padded K (for fused rbfe stage-1)
__launch_bounds__(256)
__global__ void transW16_k(const float* __restrict__ W, short* __restrict__ out) {
    int i = blockIdx.x * 256 + threadIdx.x;
    if (i >= 128 * 32) return;
    int c = i >> 5, k = i & 31;
    out[i] = (k < 16) ? f2bf(W[k * 128 + c]) : (short)0;
}

// ---------------- triplet: r10-exact (512 thr, 120KB LDS, weights in LDS) ----------------
__launch_bounds__(512)
__global__ void triplet_mfma_k(const float* __restrict__ angs, const int* __restrict__ eids,
                               const float* __restrict__ rbf0,
                               const short* __restrict__ W1f, const short* __restrict__ W2f,
                               const short* __restrict__ W3f, const float* __restrict__ upB,
                               const short* __restrict__ xdown, short* __restrict__ ysort) {
    __shared__ short wl[61440];          // 120 KB
    short* w1  = wl;                     // 12288 (96x128 frag-major)
    short* w2  = wl + 12288;             // 16384
    short* w3  = wl + 28672;             // 16384
    short* dat = wl + 45056;             // 16384 (128-row swizzled tile)

    const int tid = threadIdx.x;
    const int lane = tid & 63;
    const int w = tid >> 6;
    const int kgrp = lane >> 4;
    const int ccol = lane & 15;
    const int arow = w * 16 + ccol;
    const int cr0  = w * 16 + kgrp * 4;

    for (int i = tid; i < 1536; i += 512)
        *(uint4*)&w1[i * 8] = *(const uint4*)&W1f[i * 8];
    for (int i = tid; i < 2048; i += 512)
        *(uint4*)&w2[i * 8] = *(const uint4*)&W2f[i * 8];
    for (int i = tid; i < 2048; i += 512)
        *(uint4*)&w3[i * 8] = *(const uint4*)&W3f[i * 8];
    __syncthreads();

    float bu[8];
    #pragma unroll
    for (int c = 0; c < 8; ++c) bu[c] = upB[c * 16 + ccol];
    const short* wf1 = w1 + lane * 8;
    const short* wf2 = w2 + lane * 8;
    const short* wf3 = w3 + lane * 8;

    for (int tile = blockIdx.x; tile < NT128; tile += gridDim.x) {
        const int row0 = tile * 128;

        {
            int srow = row0 + arow;
            float cb[6], rb[16];
            if (srow < Tcnt) {
                float ang = angs[srow];
                int ge = eids[srow];
                float c1 = cosf(ang);
                cb[0] = 1.f; cb[1] = c1;
                #pragma unroll
                for (int a = 2; a < 6; ++a) cb[a] = 2.f * c1 * cb[a - 1] - cb[a - 2];
                #pragma unroll
                for (int i4 = 0; i4 < 4; ++i4) {
                    float4 r4 = *(const float4*)&rbf0[(size_t)ge * 16 + i4 * 4];
                    rb[i4*4+0] = r4.x; rb[i4*4+1] = r4.y; rb[i4*4+2] = r4.z; rb[i4*4+3] = r4.w;
                }
            } else {
                #pragma unroll
                for (int a = 0; a < 6; ++a) cb[a] = 0.f;
                #pragma unroll
                for (int q = 0; q < 16; ++q) rb[q] = 0.f;
            }
            #pragma unroll
            for (int m = 0; m < 12; ++m) {
                int v0 = kgrp * 24 + 2 * m;
                *(unsigned*)&dat[sidx(arow, 2 * v0)] =
                    pack2(cb[v0 >> 4] * rb[v0 & 15], cb[(v0 + 1) >> 4] * rb[(v0 + 1) & 15]);
            }
        }

        int eidc[4];
        #pragma unroll
        for (int j = 0; j < 4; ++j) {
            int sr = row0 + cr0 + j;
            eidc[j] = (sr < Tcnt) ? eids[sr] : -1;
        }
        short8 xds[4];
        #pragma unroll
        for (int j = 0; j < 4; ++j) {
            if (eidc[j] >= 0)
                xds[j] = *(const short8*)&xdown[(size_t)eidc[j] * 128 + ccol * 8];
            else
                xds[j] = short8{0, 0, 0, 0, 0, 0, 0, 0};
        }

        floatx4 o[8];

        // GEMM1 K=96
        {
            short8 a3[3];
            #pragma unroll
            for (int kb = 0; kb < 3; ++kb)
                a3[kb] = *(const short8*)&dat[sidx(arow, kb * 64 + kgrp * 16)];
            colmm8_lds<3>(a3, wf1, o);
            #pragma unroll
            for (int c = 0; c < 8; ++c)
                #pragma unroll
                for (int j = 0; j < 4; ++j)
                    dat[sidx(cr0 + j, 2 * (c * 16 + ccol))] = f2bf(fmaxf(o[c][j], 0.f));
        }

        // GEMM2 K=128 (* xd)
        {
            short8 a4[4];
            #pragma unroll
            for (int kb = 0; kb < 4; ++kb)
                a4[kb] = *(const short8*)&dat[sidx(arow, kb * 64 + kgrp * 16)];
            colmm8_lds<4>(a4, wf2, o);
            #pragma unroll
            for (int c = 0; c < 8; ++c)
                #pragma unroll
                for (int j = 0; j < 4; ++j)
                    dat[sidx(cr0 + j, 2 * (c * 16 + ccol))] =
                        f2bf(fmaxf(o[c][j], 0.f) * bf2f(xds[j][c]));
        }

        // GEMM3 K=128 -> ysort
        {
            short8 a4[4];
            #pragma unroll
            for (int kb = 0; kb < 4; ++kb)
                a4[kb] = *(const short8*)&dat[sidx(arow, kb * 64 + kgrp * 16)];
            colmm8_lds<4>(a4, wf3, o);
            short8 y[4];
            #pragma unroll
            for (int c = 0; c < 8; ++c)
                #pragma unroll
                for (int j = 0; j < 4; ++j)
                    y[j][c] = f2bf(fmaxf(o[c][j] + bu[c], 0.f));
            #pragma unroll
            for (int j = 0; j < 4; ++j) {
                int row = row0 + cr0 + j;
                if (row < Tcnt)
                    *(short8*)&ysort[(size_t)row * 128 + ccol * 8] = y[j];
            }
        }
    }
}

// ---------------- fused layerB (r10): CSR segment-sum + res-MLP + msg update ----------------
__launch_bounds__(256)
__global__ void layerBf_k(const short* __restrict__ ysort, const int* __restrict__ sstart,
                          const short* __restrict__ r1Wt, const float* __restrict__ r1B,
                          const short* __restrict__ r2Wt, const float* __restrict__ r2B,
                          float* __restrict__ msg) {
    __shared__ short ldsb[64 * 128];
    __shared__ float aggf[64 * 128];
    const int tid = threadIdx.x;
    const int lane = tid & 63, w = tid >> 6;
    const int row0 = blockIdx.x * 64;
    const int g16 = lane & 15;
    const int q   = lane >> 4;

    for (int it = 0; it < 16; ++it) {
        int el = it * 4 + w;
        int e = row0 + el;
        int s = sstart[e], tEnd = sstart[e + 1];
        float acc[8] = {0.f, 0.f, 0.f, 0.f, 0.f, 0.f, 0.f, 0.f};
        for (int r = s + q; r < tEnd; r += 4) {
            short8 y = *(const short8*)&ysort[(size_t)r * 128 + g16 * 8];
            #pragma unroll
            for (int c = 0; c < 8; ++c) acc[c] += bf2f(y[c]);
        }
        #pragma unroll
        for (int c = 0; c < 8; ++c) {
            acc[c] += __shfl_xor(acc[c], 16);
            acc[c] += __shfl_xor(acc[c], 32);
        }
        if (q == 0) {
            unsigned u[4];
            #pragma unroll
            for (int h = 0; h < 4; ++h) u[h] = pack2(acc[2 * h], acc[2 * h + 1]);
            *(uint4*)&ldsb[sidx(el, g16 * 16)] = make_uint4(u[0], u[1], u[2], u[3]);
            *(float4*)&aggf[el * 128 + g16 * 8]     = make_float4(acc[0], acc[1], acc[2], acc[3]);
            *(float4*)&aggf[el * 128 + g16 * 8 + 4] = make_float4(acc[4], acc[5], acc[6], acc[7]);
        }
    }
    __syncthreads();

    const int kgrp = lane >> 4, ccol = lane & 15;
    const int arow = w * 16 + ccol;
    const int cr0  = w * 16 + kgrp * 4;
    short8 a1[4];
    #pragma unroll
    for (int kb = 0; kb < 4; ++kb)
        a1[kb] = *(const short8*)&ldsb[sidx(arow, kb * 64 + kgrp * 16)];
    floatx4 o[8];
    colmm8_pf<4, 128>(a1, r1Wt + ccol * 128 + kgrp * 8, o);
    #pragma unroll
    for (int c = 0; c < 8; ++c) {
        int colg = c * 16 + ccol;
        float b1 = r1B[colg];
        #pragma unroll
        for (int j = 0; j < 4; ++j)
            ldsb[sidx(cr0 + j, 2 * colg)] = f2bf(fmaxf(o[c][j] + b1, 0.f));
    }
    short8 a2[4];
    #pragma unroll
    for (int kb = 0; kb < 4; ++kb)
        a2[kb] = *(const short8*)&ldsb[sidx(arow, kb * 64 + kgrp * 16)];
    colmm8_pf<4, 128>(a2, r2Wt + ccol * 128 + kgrp * 8, o);
    #pragma unroll
    for (int c = 0; c < 8; ++c) {
        int colg = c * 16 + ccol;
        float b2 = r2B[colg];
        #pragma unroll
        for (int j = 0; j < 4; ++j) {
            size_t ofs = (size_t)(row0 + cr0 + j) * 128 + colg;
            float ag = aggf[(cr0 + j) * 128 + ccol * 8 + c];
            msg[ofs] = msg[ofs] + ag + fmaxf(o[c][j] + b2, 0.f);
        }
    }
}

// ---------------- initial message (K=160, pad 147) ----------------
__launch_bounds__(256, 3)
__global__ void imsg_k(const float* __restrict__ af, const float* __restrict__ ef,
                       const int* __restrict__ idx_j,
                       const short* __restrict__ Wt, const float* __restrict__ bias,
                       float* __restrict__ msg) {
    __shared__ short lds[64 * 256];
    const int tid = threadIdx.x;
    const int lane = tid & 63, w = tid >> 6;
    const int row0 = blockIdx.x * 64;

    #pragma unroll
    for (int it = 0; it < 5; ++it) {
        int chunk = tid + it * 256;
        int r = chunk / 20, cg = chunk % 20;
        int row = row0 + r;
        int g = idx_j[row];
        unsigned u[4];
        #pragma unroll
        for (int h = 0; h < 4; ++h) {
            int k0 = cg * 8 + 2 * h;
            int k1 = k0 + 1;
            float f0 = (k0 < 133) ? af[(size_t)g * 133 + k0]
                     : (k0 < 147) ? ef[(size_t)row * 14 + (k0 - 133)] : 0.f;
            float f1 = (k1 < 133) ? af[(size_t)g * 133 + k1]
                     : (k1 < 147) ? ef[(size_t)row * 14 + (k1 - 133)] : 0.f;
            u[h] = pack2(f0, f1);
        }
        *(uint4*)&lds[sidxg(r, cg * 16, 256)] = make_uint4(u[0], u[1], u[2], u[3]);
    }
    __syncthreads();

    const int kgrp = lane >> 4, ccol = lane & 15;
    const int arow = w * 16 + ccol;
    const int cr0  = w * 16 + kgrp * 4;
    short8 a[5];
    #pragma unroll
    for (int kb = 0; kb < 5; ++kb)
        a[kb] = *(const short8*)&lds[sidxg(arow, kb * 64 + kgrp * 16, 256)];
    floatx4 o[8];
    colmm8_pf<5, 160>(a, Wt + ccol * 160 + kgrp * 8, o);
    #pragma unroll
    for (int c = 0; c < 8; ++c) {
        int colg = c * 16 + ccol;
        float bv = bias[colg];
        #pragma unroll
        for (int j = 0; j < 4; ++j)
            msg[(size_t)(row0 + cr0 + j) * 128 + colg] = fmaxf(o[c][j] + bv, 0.f);
    }
}

// ---------------- layerA (r10: streaming weights) ----------------
__launch_bounds__(256, 3)
__global__ void layerA_k(const float* __restrict__ msg, const short* __restrict__ rbfe,
                         const short* __restrict__ kjWt, const float* __restrict__ kjB,
                         const short* __restrict__ rbf2Wt, const float* __restrict__ rbf2B,
                         const short* __restrict__ downWt, const float* __restrict__ downB,
                         short* __restrict__ xdown) {
    __shared__ short ldsM[64 * 128];
    __shared__ short ldsR[64 * 128];
    const int tid = threadIdx.x;
    const int lane = tid & 63, w = tid >> 6;
    const size_t row0 = (size_t)blockIdx.x * 64;
    stage64x128(msg, row0, ldsM, tid);
    stage_bf(rbfe, row0, ldsR, tid);
    __syncthreads();
    const int kgrp = lane >> 4, ccol = lane & 15;
    const int arow = w * 16 + ccol;
    const int cr0  = w * 16 + kgrp * 4;
    short8 aM[4], aR[4];
    #pragma unroll
    for (int kb = 0; kb < 4; ++kb) {
        aM[kb] = *(const short8*)&ldsM[sidx(arow, kb * 64 + kgrp * 16)];
        aR[kb] = *(const short8*)&ldsR[sidx(arow, kb * 64 + kgrp * 16)];
    }
    floatx4 oR[8], oK[8];
    colmm8_pf<4, 128>(aR, rbf2Wt + ccol * 128 + kgrp * 8, oR);
    colmm8_pf<4, 128>(aM, kjWt   + ccol * 128 + kgrp * 8, oK);
    #pragma unroll
    for (int c = 0; c < 8; ++c) {
        int colg = c * 16 + ccol;
        float rb = rbf2B[colg], kbb = kjB[colg];
        #pragma unroll
        for (int j = 0; j < 4; ++j) {
            float x = fmaxf(oK[c][j] + kbb, 0.f) * fmaxf(oR[c][j] + rb, 0.f);
            ldsM[sidx(cr0 + j, 2 * colg)] = f2bf(x);
        }
    }
    short8 aX[4];
    #pragma unroll
    for (int kb = 0; kb < 4; ++kb)
        aX[kb] = *(const short8*)&ldsM[sidx(arow, kb * 64 + kgrp * 16)];
    colmm8_pf<4, 128>(aX, downWt + ccol * 128 + kgrp * 8, oK);
    #pragma unroll
    for (int j = 0; j < 4; ++j) {
        short8 v;
        #pragma unroll
        for (int c = 0; c < 8; ++c)
            v[c] = f2bf(fmaxf(oK[c][j] + downB[c * 16 + ccol], 0.f));
        *(short8*)&xdown[(row0 + cr0 + j) * 128 + ccol * 8] = v;
    }
}

// ---------------- rbfe FUSED: rbf_h = relu(rbf0@W16+b16) (K=32 padded, in-kernel)
// then out = relu(rbf_h @ W3 + b + P1[t(i)] + P2[t(j)]), bf16 out ----------------
__launch_bounds__(256, 3)
__global__ void rbfe_k(const float* __restrict__ rbf0, const short* __restrict__ W16,
                       const float* __restrict__ b16, const short* __restrict__ W3t,
                       const float* __restrict__ bias,
                       const int* __restrict__ idx_i, const int* __restrict__ idx_j,
                       const int* __restrict__ atype,
                       const float* __restrict__ P1, const float* __restrict__ P2,
                       short* __restrict__ out) {
    __shared__ short lds[64 * 128];
    const int tid = threadIdx.x;
    const int lane = tid & 63, w = tid >> 6;
    const int row0 = blockIdx.x * 64;
    const int kgrp = lane >> 4, ccol = lane & 15;
    const int arow = w * 16 + ccol;
    const int cr0  = w * 16 + kgrp * 4;

    // stage 1: rbf_h tile via K=32 (zero-padded) MFMA; A-frag from rbf0 directly
    {
        short8 a0;
        if (kgrp < 2) {
            int grow = row0 + arow;
            float4 r0 = *(const float4*)&rbf0[(size_t)grow * 16 + kgrp * 8];
            float4 r1 = *(const float4*)&rbf0[(size_t)grow * 16 + kgrp * 8 + 4];
            a0[0] = f2bf(r0.x); a0[1] = f2bf(r0.y); a0[2] = f2bf(r0.z); a0[3] = f2bf(r0.w);
            a0[4] = f2bf(r1.x); a0[5] = f2bf(r1.y); a0[6] = f2bf(r1.z); a0[7] = f2bf(r1.w);
        } else {
            a0 = short8{0, 0, 0, 0, 0, 0, 0, 0};
        }
        floatx4 o[8];
        colmm8_pf<1, 32>(&a0, W16 + ccol * 32 + kgrp * 8, o);
        #pragma unroll
        for (int c = 0; c < 8; ++c) {
            float bv = b16[c * 16 + ccol];
            #pragma unroll
            for (int j = 0; j < 4; ++j)
                lds[sidx(cr0 + j, 2 * (c * 16 + ccol))] = f2bf(fmaxf(o[c][j] + bv, 0.f));
        }
    }
    // band-local: writes cover rows [w*16,w*16+16); reads below stay in band -> no barrier

    const float* p1p[4]; const float* p2p[4];
    #pragma unroll
    for (int j = 0; j < 4; ++j) {
        int row = row0 + cr0 + j;
        p1p[j] = P1 + (size_t)atype[idx_i[row]] * 128;
        p2p[j] = P2 + (size_t)atype[idx_j[row]] * 128;
    }
    short8 a[4];
    #pragma unroll
    for (int kb = 0; kb < 4; ++kb)
        a[kb] = *(const short8*)&lds[sidx(arow, kb * 64 + kgrp * 16)];
    floatx4 o[8];
    colmm8_pf<4, 128>(a, W3t + ccol * 128 + kgrp * 8, o);
    #pragma unroll
    for (int c = 0; c < 8; ++c) {
        int colg = c * 16 + ccol;
        float bv = bias[colg];
        #pragma unroll
        for (int j = 0; j < 4; ++j)
            out[(size_t)(row0 + cr0 + j) * 128 + colg] =
                f2bf(fmaxf(o[c][j] + bv + p1p[j][colg] + p2p[j][colg], 0.f));
    }
}

// ---------------- concat GEMM (fp32, final projection only) ----------------
__launch_bounds__(256)
__global__ void concatgemm_k(const float* __restrict__ IN1, int K1,
                             const float* __restrict__ IN2, int K2,
                             const float* __restrict__ W, const float* __restrict__ bias,
                             float* __restrict__ Y, int M) {
    __shared__ float xs[96 * 68];
    const int tid = threadIdx.x;
    const int row0 = blockIdx.x * 64;
    const int col8 = (tid & 15) * 8;
    const int r0 = (tid >> 4) * 4;
    const int K = K1 + K2;

    float acc[4][8];
    #pragma unroll
    for (int r = 0; r < 4; ++r)
        #pragma unroll
        for (int c = 0; c < 8; ++c) acc[r][c] = 0.f;

    for (int kb = 0; kb < K; kb += 96) {
        int kc = (K - kb < 96) ? (K - kb) : 96;
        __syncthreads();
        for (int idx = tid; idx < 64 * 96; idx += 256) {
            int r = idx / 96, kl = idx % 96;
            if (kl < kc) {
                int row = row0 + r;
                float v = 0.f;
                if (row < M) {
                    int kg = kb + kl;
                    v = (kg < K1) ? IN1[(size_t)row * K1 + kg]
                                  : IN2[(size_t)row * K2 + (kg - K1)];
                }
                xs[kl * 68 + r] = v;
            }
        }
        __syncthreads();
        for (int k = 0; k < kc; ++k) {
            float4 xv = *(const float4*)&xs[k * 68 + r0];
            const float* wr = &W[(size_t)(kb + k) * 128 + col8];
            float4 w0 = *(const float4*)wr;
            float4 w1 = *(const float4*)(wr + 4);
            float xr[4] = {xv.x, xv.y, xv.z, xv.w};
            float wc[8] = {w0.x, w0.y, w0.z, w0.w, w1.x, w1.y, w1.z, w1.w};
            #pragma unroll
            for (int r = 0; r < 4; ++r)
                #pragma unroll
                for (int c = 0; c < 8; ++c)
                    acc[r][c] = fmaf(xr[r], wc[c], acc[r][c]);
        }
    }

    float4 b0 = *(const float4*)&bias[col8];
    float4 b1 = *(const float4*)&bias[col8 + 4];
    float bb[8] = {b0.x, b0.y, b0.z, b0.w, b1.x, b1.y, b1.z, b1.w};
    #pragma unroll
    for (int r = 0; r < 4; ++r) {
        int row = row0 + r0 + r;
        if (row >= M) continue;
        float v[8];
        #pragma unroll
        for (int c = 0; c < 8; ++c) v[c] = fmaxf(acc[r][c] + bb[c], 0.f);
        *(float4*)&Y[(size_t)row * 128 + col8]     = make_float4(v[0], v[1], v[2], v[3]);
        *(float4*)&Y[(size_t)row * 128 + col8 + 4] = make_float4(v[4], v[5], v[6], v[7]);
    }
}

// ---------------- host ----------------

extern "C" void kernel_launch(void* const* d_in, const int* in_sizes, int n_in,
                              void* d_out, int out_size, void* d_ws, size_t ws_size,
                              hipStream_t stream) {
    const float* atom_feature = (const float*)d_in[0];
    const float* edge_feature = (const float*)d_in[1];
    const float* dist         = (const float*)d_in[2];
    const float* angle        = (const float*)d_in[3];
    const float* W_i1_w       = (const float*)d_in[4];
    const float* W_i1_b       = (const float*)d_in[5];
    const float* emb_table    = (const float*)d_in[6];
    const float* lin_rbf_w    = (const float*)d_in[7];
    const float* lin_rbf_b    = (const float*)d_in[8];
    const float* lin_emb_w    = (const float*)d_in[9];
    const float* lin_emb_b    = (const float*)d_in[10];
    const float* bessel_freq  = (const float*)d_in[11];
    const float* L_rbf2_w     = (const float*)d_in[12];
    const float* L_rbf2_b     = (const float*)d_in[13];
    const float* L_kj_w       = (const float*)d_in[14];
    const float* L_kj_b       = (const float*)d_in[15];
    const float* L_sbf1_w     = (const float*)d_in[16];
    const float* L_sbf2_w     = (const float*)d_in[17];
    const float* L_down_w     = (const float*)d_in[18];
    const float* L_down_b     = (const float*)d_in[19];
    const float* L_up_w       = (const float*)d_in[20];
    const float* L_up_b       = (const float*)d_in[21];
    const float* L_res1_w     = (const float*)d_in[22];
    const float* L_res1_b     = (const float*)d_in[23];
    const float* L_res2_w     = (const float*)d_in[24];
    const float* L_res2_b     = (const float*)d_in[25];
    const float* W_o_w        = (const float*)d_in[26];
    const float* W_o_b        = (const float*)d_in[27];
    const int* idx_i          = (const int*)d_in[28];
    const int* idx_j          = (const int*)d_in[29];
    const int* idx_kj         = (const int*)d_in[30];
    const int* ib_eid         = (const int*)d_in[32];
    const int* ib_atom        = (const int*)d_in[33];

    float* ws = (float*)d_ws;
    size_t off = 0;
    auto take = [&](size_t n) { float* p = ws + off; off += n; return p; };
    float* msg    = take((size_t)Ecnt * 128);
    short* rbfe   = (short*)take((size_t)Ecnt * 64);
    short* sxd    = (short*)take((size_t)Ecnt * 64);
    short* ysort  = (short*)take((size_t)Tcnt * 64);
    float* rbf0b  = take((size_t)Ecnt * 16);
    float* P1     = take(100 * 128);
    float* P2     = take(100 * 128);
    int*   atyp   = (int*)take(Ncnt);
    int*   cnts   = (int*)take(Ecnt);
    int*   sstart = (int*)take(Ecnt + 1);
    int*   cur    = (int*)take(Ecnt);
    int*   btot   = (int*)take(512);
    int*   boff   = (int*)take(512);
    int*   eids   = (int*)take(Tcnt);
    float* angs   = take(Tcnt);
    int*   sstartA= (int*)take(Ncnt + 1);
    int*   eidsA  = (int*)take(Ecnt);
    short* wts    = (short*)take(160100);

    if (off * sizeof(float) > ws_size) {
        sentinel_k<<<1, 256, 0, stream>>>((float*)d_out, (float)ws_size);
        return;
    }

    float* atomm = (float*)ysort;   // alias: ysort dead after last layerBf

    const int GE  = Ecnt / 64;
    const int GN  = (Ncnt + 63) / 64;
    const int NBE = (Ecnt + 255) / 256;   // 469
    const int NBT = (Tcnt + 255) / 256;
    const int NBA = (Ncnt + 255) / 256;   // 59

    atype_k<<<(Ncnt + 255) / 256, 256, 0, stream>>>(atom_feature, atyp);
    pemb_k<<<100, 128, 0, stream>>>(emb_table, lin_emb_w, P1, P2);
    rbf0_k<<<NBE, 256, 0, stream>>>(dist, bessel_freq, rbf0b);

    // --- edge CSR sort (triplets by target edge) ---
    hipMemsetAsync(cnts, 0, (size_t)Ecnt * sizeof(int), stream);
    hist_k<<<NBT, 256, 0, stream>>>(idx_kj, cnts, Tcnt);
    scan1_k<<<NBE, 256, 0, stream>>>(cnts, btot, Ecnt);
    scan2_k<<<1, 512, 0, stream>>>(btot, boff, NBE);
    scan3_k<<<NBE, 256, 0, stream>>>(cnts, boff, sstart, cur, Ecnt, Tcnt);
    perm_k<<<NBT, 256, 0, stream>>>(idx_kj, angle, cur, eids, angs);

    // --- atom CSR sort (incoming edges by atom; reuses cnts/btot/boff/cur) ---
    hipMemsetAsync(cnts, 0, (size_t)Ncnt * sizeof(int), stream);
    hist_k<<<NBE, 256, 0, stream>>>(ib_atom, cnts, Ecnt);
    scan1_k<<<NBA, 256, 0, stream>>>(cnts, btot, Ncnt);
    scan2_k<<<1, 512, 0, stream>>>(btot, boff, NBA);
    scan3_k<<<NBA, 256, 0, stream>>>(cnts, boff, sstartA, cur, Ncnt, Ecnt);
    permA_k<<<NBE, 256, 0, stream>>>(ib_atom, ib_eid, cur, eidsA);

    // --- weight prep ---
    short* p = wts;
    short* wt1[2]; short* wt2[2]; short* wt3[2];
    short* wkj[2]; short* wr2f[2]; short* wdn[2]; short* wr1[2]; short* wr2[2];
    for (int l = 0; l < 2; ++l) {
        wt1[l] = p; p += 96 * 128;
        wt2[l] = p; p += 128 * 128;
        wt3[l] = p; p += 128 * 128;
        wkj[l] = p; p += 128 * 128;
        wr2f[l] = p; p += 128 * 128;
        wdn[l] = p; p += 128 * 128;
        wr1[l] = p; p += 128 * 128;
        wr2[l] = p; p += 128 * 128;
    }
    short* wemb3 = p; p += 128 * 128;
    short* wi1t  = p; p += 128 * 160;
    short* w16   = p; p += 128 * 32;

    WPack wp;
    int m = 0;
    for (int l = 0; l < 2; ++l) {
        wp.src[m] = L_kj_w   + (size_t)l * 128 * 128; wp.dst[m] = wkj[l];  wp.perm[m++] = 0;
        wp.src[m] = L_rbf2_w + (size_t)l * 128 * 128; wp.dst[m] = wr2f[l]; wp.perm[m++] = 0;
        wp.src[m] = L_down_w + (size_t)l * 128 * 128; wp.dst[m] = wdn[l];  wp.perm[m++] = 0;
        wp.src[m] = L_res1_w + (size_t)l * 128 * 128; wp.dst[m] = wr1[l];  wp.perm[m++] = 1;
        wp.src[m] = L_res2_w + (size_t)l * 128 * 128; wp.dst[m] = wr2[l];  wp.perm[m++] = 0;
    }
    wp.src[m] = lin_emb_w + 256 * 128; wp.dst[m] = wemb3; wp.perm[m++] = 0;   // 11
    transmany_k<<<11 * 64, 256, 0, stream>>>(wp);

    FPack fp;
    m = 0;
    for (int l = 0; l < 2; ++l) {
        fp.src[m] = L_sbf1_w + (size_t)l * 96 * 128;  fp.dst[m] = wt1[l]; fp.nkb[m++] = 3;
        fp.src[m] = L_sbf2_w + (size_t)l * 128 * 128; fp.dst[m] = wt2[l]; fp.nkb[m++] = 4;
        fp.src[m] = L_up_w   + (size_t)l * 128 * 128; fp.dst[m] = wt3[l]; fp.nkb[m++] = 4;
    }
    transfragall_k<<<6 * 64, 256, 0, stream>>>(fp);
    transWi1_k<<<(128 * 160 + 255) / 256, 256, 0, stream>>>(W_i1_w, wi1t);
    transW16_k<<<16, 256, 0, stream>>>(lin_rbf_w, w16);

    // --- initial message + fused rbf_e ---
    imsg_k<<<GE, 256, 0, stream>>>(atom_feature, edge_feature, idx_j, wi1t, W_i1_b, msg);
    rbfe_k<<<GE, 256, 0, stream>>>(rbf0b, w16, lin_rbf_b, wemb3, lin_emb_b,
                                   idx_i, idx_j, atyp, P1, P2, rbfe);

    for (int l = 0; l < 2; ++l) {
        layerA_k<<<GE, 256, 0, stream>>>(msg, rbfe,
                                         wkj[l], L_kj_b + (size_t)l * 128,
                                         wr2f[l], L_rbf2_b + (size_t)l * 128,
                                         wdn[l], L_down_b + (size_t)l * 128, sxd);
        triplet_mfma_k<<<512, 512, 0, stream>>>(angs, eids, rbf0b,
                                                wt1[l], wt2[l], wt3[l],
                                                L_up_b + (size_t)l * 128, sxd, ysort);
        layerBf_k<<<GE, 256, 0, stream>>>(ysort, sstart,
                                          wr1[l], L_res1_b + (size_t)l * 128,
                                          wr2[l], L_res2_b + (size_t)l * 128, msg);
    }

    // atom aggregation (CSR, no atomics) + final projection
    atomsum_k<<<(Ncnt * 128) / 256, 256, 0, stream>>>(msg, eidsA, sstartA, atomm);
    concatgemm_k<<<GN, 256, 0, stream>>>(atom_feature, 133, atomm, 128,
                                         W_o_w, W_o_b, (float*)d_out, Ncnt);
}

// Round 14
// 984.550 us; speedup vs baseline: 1.3577x; 1.0779x over previous
//
#include <hip/hip_runtime.h>
#include <hip/hip_bf16.h>

#define Ecnt 120000
#define Ncnt 15000
#define Tcnt 500000
#define NT256 ((Tcnt + 255) / 256)

typedef __attribute__((ext_vector_type(8))) short short8;
typedef __attribute__((ext_vector_type(4))) float floatx4;

__device__ __forceinline__ floatx4 mfma16(short8 a, short8 b, floatx4 c) {
    return __builtin_amdgcn_mfma_f32_16x16x32_bf16(a, b, c, 0, 0, 0);
}

__device__ __forceinline__ short f2bf(float f) {
    __hip_bfloat16 b = __float2bfloat16(f);
    short s;
    __builtin_memcpy(&s, &b, 2);
    return s;
}

__device__ __forceinline__ float bf2f(short s) {
    unsigned u = ((unsigned)(unsigned short)s) << 16;
    float f;
    __builtin_memcpy(&f, &u, 4);
    return f;
}

__device__ __forceinline__ unsigned pack2(float x, float y) {
    return (unsigned)(unsigned short)f2bf(x) | ((unsigned)(unsigned short)f2bf(y) << 16);
}

// bf16 MFMA tile swizzle: byte-col XOR (row&15)<<4, BOTH sides.
__device__ __forceinline__ int sidx(int row, int bc) {
    return row * 128 + (((bc) ^ ((row & 15) << 4)) >> 1);
}
__device__ __forceinline__ int sidxg(int row, int bc, int ldshorts) {
    return row * ldshorts + (((bc) ^ ((row & 15) << 4)) >> 1);
}

__device__ __forceinline__ void stage64x128(const float* __restrict__ src, size_t row0,
                                            short* __restrict__ lds, int tid) {
    #pragma unroll
    for (int it = 0; it < 8; ++it) {
        int chunk = tid + it * 256;
        int r = chunk >> 5, c4 = chunk & 31;
        float4 v = *(const float4*)&src[(row0 + r) * 128 + c4 * 4];
        *(uint2*)&lds[sidx(r, c4 * 8)] = make_uint2(pack2(v.x, v.y), pack2(v.z, v.w));
    }
}

__device__ __forceinline__ void stage_bf(const short* __restrict__ src, size_t row0,
                                         short* __restrict__ lds, int tid) {
    #pragma unroll
    for (int it = 0; it < 4; ++it) {
        int chunk = tid + it * 256;
        int r = chunk >> 4, cg = chunk & 15;
        uint4 v = *(const uint4*)&src[(row0 + r) * 128 + cg * 8];
        *(uint4*)&lds[sidx(r, cg * 16)] = v;
    }
}

// global-weight 8-col GEMM with 2-deep prefetch
template<int NKB, int K>
__device__ __forceinline__ void colmm8_pf(const short8 a[NKB], const short* __restrict__ wcol,
                                          floatx4 out[8]) {
    short8 w[2][NKB];
    #pragma unroll
    for (int kb = 0; kb < NKB; ++kb) w[0][kb] = *(const short8*)(wcol + kb * 32);
    #pragma unroll
    for (int kb = 0; kb < NKB; ++kb) w[1][kb] = *(const short8*)(wcol + 16 * K + kb * 32);
    #pragma unroll
    for (int c = 0; c < 8; ++c) {
        floatx4 acc = {0.f, 0.f, 0.f, 0.f};
        #pragma unroll
        for (int kb = 0; kb < NKB; ++kb) acc = mfma16(a[kb], w[c & 1][kb], acc);
        out[c] = acc;
        if (c + 2 < 8) {
            #pragma unroll
            for (int kb = 0; kb < NKB; ++kb)
                w[c & 1][kb] = *(const short8*)(wcol + (size_t)(c + 2) * 16 * K + kb * 32);
        }
    }
}

// LDS fragment-major 8-col GEMM, single row-group
template<int NKB>
__device__ __forceinline__ void colmm8_lds(const short8 a[NKB], const short* __restrict__ wf,
                                           floatx4 out[8]) {
    short8 w[2][NKB];
    #pragma unroll
    for (int kb = 0; kb < NKB; ++kb) w[0][kb] = *(const short8*)(wf + kb * 512);
    #pragma unroll
    for (int kb = 0; kb < NKB; ++kb) w[1][kb] = *(const short8*)(wf + (NKB + kb) * 512);
    #pragma unroll
    for (int c = 0; c < 8; ++c) {
        floatx4 acc = {0.f, 0.f, 0.f, 0.f};
        #pragma unroll
        for (int kb = 0; kb < NKB; ++kb) acc = mfma16(a[kb], w[c & 1][kb], acc);
        out[c] = acc;
        if (c + 2 < 8) {
            #pragma unroll
            for (int kb = 0; kb < NKB; ++kb)
                w[c & 1][kb] = *(const short8*)(wf + ((c + 2) * NKB + kb) * 512);
        }
    }
}

// LDS fragment-major 8-col GEMM, DUAL row-group: each weight frag feeds 2 MFMAs.
template<int NKB, typename Epi>
__device__ __forceinline__ void colmm8_dual_lds(const short8 a0[NKB], const short8 a1[NKB],
                                                const short* __restrict__ wf, Epi epi) {
    short8 w[2][NKB];
    #pragma unroll
    for (int kb = 0; kb < NKB; ++kb) w[0][kb] = *(const short8*)(wf + kb * 512);
    #pragma unroll
    for (int kb = 0; kb < NKB; ++kb) w[1][kb] = *(const short8*)(wf + (NKB + kb) * 512);
    #pragma unroll
    for (int c = 0; c < 8; ++c) {
        floatx4 acc0 = {0.f, 0.f, 0.f, 0.f};
        floatx4 acc1 = {0.f, 0.f, 0.f, 0.f};
        #pragma unroll
        for (int kb = 0; kb < NKB; ++kb) {
            acc0 = mfma16(a0[kb], w[c & 1][kb], acc0);
            acc1 = mfma16(a1[kb], w[c & 1][kb], acc1);
        }
        epi(c, acc0, acc1);
        if (c + 2 < 8) {
            #pragma unroll
            for (int kb = 0; kb < NKB; ++kb)
                w[c & 1][kb] = *(const short8*)(wf + ((c + 2) * NKB + kb) * 512);
        }
    }
}

// ---------------- small kernels ----------------

__launch_bounds__(256)
__global__ void sentinel_k(float* o, float v) { o[0] = v; }

__launch_bounds__(256)
__global__ void atype_k(const float* __restrict__ af, int* __restrict__ atype) {
    int n = blockIdx.x * 256 + threadIdx.x;
    if (n >= Ncnt) return;
    const float* r = af + (size_t)n * 133;
    int best = 0; float bv = r[0];
    for (int k = 1; k < 100; ++k) { float v = r[k]; if (v > bv) { bv = v; best = k; } }
    atype[n] = best;
}

__launch_bounds__(128)
__global__ void pemb_k(const float* __restrict__ emb, const float* __restrict__ W,
                       float* __restrict__ P1, float* __restrict__ P2) {
    int r = blockIdx.x, c = threadIdx.x;
    __shared__ float er[128];
    er[c] = emb[r * 128 + c];
    __syncthreads();
    float a1 = 0.f, a2 = 0.f;
    for (int k = 0; k < 128; ++k) {
        float e = er[k];
        a1 = fmaf(e, W[k * 128 + c], a1);
        a2 = fmaf(e, W[(128 + k) * 128 + c], a2);
    }
    P1[r * 128 + c] = a1;
    P2[r * 128 + c] = a2;
}

__launch_bounds__(256)
__global__ void rbf0_k(const float* __restrict__ dist, const float* __restrict__ freq,
                       float* __restrict__ rbf0) {
    int e = blockIdx.x * 256 + threadIdx.x;
    if (e >= Ecnt) return;
    float x = dist[e] * 0.125f;
    float x2 = x * x;
    float x5 = x2 * x2 * x;
    float env = 1.f / x - 28.f * x5 + 48.f * x5 * x - 21.f * x5 * x2;
    if (!(x < 1.f)) env = 0.f;
    #pragma unroll
    for (int r = 0; r < 16; ++r)
        rbf0[(size_t)e * 16 + r] = env * sinf(freq[r] * x);
}

__launch_bounds__(256)
__global__ void atomsum_k(const float* __restrict__ msg, const int* __restrict__ eidsA,
                          const int* __restrict__ sstartA, float* __restrict__ am) {
    int gid = blockIdx.x * 256 + threadIdx.x;
    int a = gid >> 7, c = gid & 127;
    int s = sstartA[a], e = sstartA[a + 1];
    float acc = 0.f;
    for (int r = s; r < e; ++r)
        acc += msg[(size_t)eidsA[r] * 128 + c];
    am[(size_t)a * 128 + c] = acc;
}

// ---------------- sorting (generic CSR) ----------------

__launch_bounds__(256)
__global__ void hist_k(const int* __restrict__ idx, int* __restrict__ cnt, int n) {
    int t = blockIdx.x * 256 + threadIdx.x;
    if (t < n) atomicAdd(&cnt[idx[t]], 1);
}

__launch_bounds__(256)
__global__ void scan1_k(int* __restrict__ cnt, int* __restrict__ btot, int n) {
    __shared__ int s[256];
    int t = threadIdx.x, i = blockIdx.x * 256 + t;
    int v = (i < n) ? cnt[i] : 0;
    s[t] = v;
    #pragma unroll
    for (int off = 1; off < 256; off <<= 1) {
        __syncthreads();
        int nv = (t >= off) ? s[t - off] + s[t] : s[t];
        __syncthreads();
        s[t] = nv;
    }
    if (i < n) cnt[i] = s[t] - v;
    if (t == 255) btot[blockIdx.x] = s[255];
}

__launch_bounds__(512)
__global__ void scan2_k(const int* __restrict__ btot, int* __restrict__ boff, int nb) {
    __shared__ int s[512];
    int t = threadIdx.x;
    int v = (t < nb) ? btot[t] : 0;
    s[t] = v;
    #pragma unroll
    for (int off = 1; off < 512; off <<= 1) {
        __syncthreads();
        int nv = (t >= off) ? s[t - off] + s[t] : s[t];
        __syncthreads();
        s[t] = nv;
    }
    if (t < nb) boff[t] = s[t] - v;
}

__launch_bounds__(256)
__global__ void scan3_k(const int* __restrict__ basep, const int* __restrict__ boff,
                        int* __restrict__ sstart, int* __restrict__ cur, int n, int total) {
    int i = blockIdx.x * 256 + threadIdx.x;
    if (i < n) {
        int v = basep[i] + boff[i >> 8];
        sstart[i] = v;
        cur[i] = v;
    }
    if (i == 0) sstart[n] = total;
}

__launch_bounds__(256)
__global__ void perm_k(const int* __restrict__ idx, const float* __restrict__ angle,
                       int* __restrict__ cur, int* __restrict__ eids,
                       float* __restrict__ angs) {
    int t = blockIdx.x * 256 + threadIdx.x;
    if (t >= Tcnt) return;
    int e = idx[t];
    int p = atomicAdd(&cur[e], 1);
    eids[p] = e;
    angs[p] = angle[t];
}

__launch_bounds__(256)
__global__ void permA_k(const int* __restrict__ aid, const int* __restrict__ eid,
                        int* __restrict__ cur, int* __restrict__ eidsA) {
    int t = blockIdx.x * 256 + threadIdx.x;
    if (t >= Ecnt) return;
    int p = atomicAdd(&cur[aid[t]], 1);
    eidsA[p] = eid[t];
}

// ---------------- weight conversion (batched) ----------------

struct WPack {
    const float* src[11];
    short* dst[11];
    int perm[11];
};
__launch_bounds__(256)
__global__ void transmany_k(WPack p) {
    int m = blockIdx.x >> 6;
    int i = ((blockIdx.x & 63) << 8) + threadIdx.x;
    int c = i & 127, pi = i >> 7;
    int k = p.perm[m] ? ((pi & 7) * 16 + (pi >> 3)) : pi;
    p.dst[m][c * 128 + pi] = f2bf(p.src[m][(size_t)k * 128 + c]);
}

struct FPack {
    const float* src[6];
    short* dst[6];
    int nkb[6];
};
__launch_bounds__(256)
__global__ void transfragall_k(FPack p) {
    int m = blockIdx.x >> 6;
    int i = ((blockIdx.x & 63) << 8) + threadIdx.x;
    int NKB = p.nkb[m];
    if (i >= NKB * 4096) return;
    int e = i & 7;
    int lane = (i >> 3) & 63;
    int ckb = i >> 9;
    int c = ckb / NKB, kb = ckb - c * NKB;
    int n = c * 16 + (lane & 15);
    int k = kb * 32 + (lane >> 4) * 8 + e;
    p.dst[m][i] = f2bf(p.src[m][(size_t)k * 128 + n]);
}

__launch_bounds__(256)
__global__ void transWi1_k(const float* __restrict__ W, short* __restrict__ out) {
    int i = blockIdx.x * 256 + threadIdx.x;
    if (i >= 128 * 160) return;
    int c = i / 160, k = i % 160;
    out[i] = (k < 147) ? f2bf(W[k * 128 + c]) : (short)0;
}

__launch_bounds__(256)
__global__ void transW16_k(const float* __restrict__ W, short* __restrict__ out) {
    int i = blockIdx.x * 256 + threadIdx.x;
    if (i >= 128 * 32) return;
    int c = i >> 5, k = i & 31;
    out[i] = (k < 16) ? f2bf(W[k * 128 + c]) : (short)0;
}

// ---------------- triplet: 512 thr, 256-row tile, LDS weights, DUAL row-group ----------------
// Wave w owns rows [w*32, w*32+32) as two 16-row groups through all 3 GEMMs
// (band-local staging r=tid>>1 -> no per-tile barrier).  Each LDS weight
// fragment read feeds TWO MFMAs (2:1 MFMA:ds_read).
__launch_bounds__(512)
__global__ void triplet_mfma_k(const float* __restrict__ angs, const int* __restrict__ eids,
                               const float* __restrict__ rbf0,
                               const short* __restrict__ W1f, const short* __restrict__ W2f,
                               const short* __restrict__ W3f, const float* __restrict__ upB,
                               const short* __restrict__ xdown, short* __restrict__ ysort) {
    __shared__ short wl[77824];          // 152 KB
    short* w1  = wl;                     // 12288 shorts (96x128 frag-major)
    short* w2  = wl + 12288;             // 16384
    short* w3  = wl + 28672;             // 16384
    short* dat = wl + 45056;             // 32768 (256-row swizzled tile)

    const int tid = threadIdx.x;
    const int lane = tid & 63;
    const int w = tid >> 6;               // 0..7
    const int kgrp = lane >> 4;
    const int ccol = lane & 15;
    const int ar0 = w * 32 + ccol;
    const int ar1 = w * 32 + 16 + ccol;
    const int cb0 = w * 32 + kgrp * 4;
    const int cb1 = w * 32 + 16 + kgrp * 4;

    for (int i = tid; i < 1536; i += 512)
        *(uint4*)&w1[i * 8] = *(const uint4*)&W1f[i * 8];
    for (int i = tid; i < 2048; i += 512)
        *(uint4*)&w2[i * 8] = *(const uint4*)&W2f[i * 8];
    for (int i = tid; i < 2048; i += 512)
        *(uint4*)&w3[i * 8] = *(const uint4*)&W3f[i * 8];
    __syncthreads();

    float bu[8];
    #pragma unroll
    for (int c = 0; c < 8; ++c) bu[c] = upB[c * 16 + ccol];
    const short* wf1 = w1 + lane * 8;
    const short* wf2 = w2 + lane * 8;
    const short* wf3 = w3 + lane * 8;

    for (int tile = blockIdx.x; tile < NT256; tile += gridDim.x) {
        const int row0 = tile * 256;

        // band-local staging: thread stages half a row (48 bf16 cols), r = tid>>1;
        // wave w's threads cover rows [w*32, w*32+32) == its compute bands.
        {
            int r = tid >> 1, h = tid & 1;
            int srow = row0 + r;
            float cb[6], rb[16];
            if (srow < Tcnt) {
                float ang = angs[srow];
                int ge = eids[srow];
                float c1 = cosf(ang);
                cb[0] = 1.f; cb[1] = c1;
                #pragma unroll
                for (int a = 2; a < 6; ++a) cb[a] = 2.f * c1 * cb[a - 1] - cb[a - 2];
                #pragma unroll
                for (int i4 = 0; i4 < 4; ++i4) {
                    float4 r4 = *(const float4*)&rbf0[(size_t)ge * 16 + i4 * 4];
                    rb[i4*4+0] = r4.x; rb[i4*4+1] = r4.y; rb[i4*4+2] = r4.z; rb[i4*4+3] = r4.w;
                }
            } else {
                #pragma unroll
                for (int a = 0; a < 6; ++a) cb[a] = 0.f;
                #pragma unroll
                for (int q = 0; q < 16; ++q) rb[q] = 0.f;
            }
            #pragma unroll
            for (int m = 0; m < 24; ++m) {
                int v0 = h * 48 + 2 * m;
                *(unsigned*)&dat[sidx(r, 2 * v0)] =
                    pack2(cb[v0 >> 4] * rb[v0 & 15], cb[(v0 + 1) >> 4] * rb[(v0 + 1) & 15]);
            }
        }

        // xdown gather for both bands (issued early)
        short8 xds[2][4];
        #pragma unroll
        for (int g = 0; g < 2; ++g)
            #pragma unroll
            for (int j = 0; j < 4; ++j) {
                int sr = row0 + (g ? cb1 : cb0) + j;
                if (sr < Tcnt) {
                    int e = eids[sr];
                    xds[g][j] = *(const short8*)&xdown[(size_t)e * 128 + ccol * 8];
                } else {
                    xds[g][j] = short8{0, 0, 0, 0, 0, 0, 0, 0};
                }
            }

        // GEMM1 K=96 dual
        {
            short8 a0[3], a1[3];
            #pragma unroll
            for (int kb = 0; kb < 3; ++kb) {
                a0[kb] = *(const short8*)&dat[sidx(ar0, kb * 64 + kgrp * 16)];
                a1[kb] = *(const short8*)&dat[sidx(ar1, kb * 64 + kgrp * 16)];
            }
            colmm8_dual_lds<3>(a0, a1, wf1,
                [&](int c, floatx4 A0, floatx4 A1) {
                    int bc = 2 * (c * 16 + ccol);
                    #pragma unroll
                    for (int j = 0; j < 4; ++j) {
                        dat[sidx(cb0 + j, bc)] = f2bf(fmaxf(A0[j], 0.f));
                        dat[sidx(cb1 + j, bc)] = f2bf(fmaxf(A1[j], 0.f));
                    }
                });
        }

        // GEMM2 K=128 dual (* xd)
        {
            short8 a0[4], a1[4];
            #pragma unroll
            for (int kb = 0; kb < 4; ++kb) {
                a0[kb] = *(const short8*)&dat[sidx(ar0, kb * 64 + kgrp * 16)];
                a1[kb] = *(const short8*)&dat[sidx(ar1, kb * 64 + kgrp * 16)];
            }
            colmm8_dual_lds<4>(a0, a1, wf2,
                [&](int c, floatx4 A0, floatx4 A1) {
                    int bc = 2 * (c * 16 + ccol);
                    #pragma unroll
                    for (int j = 0; j < 4; ++j) {
                        dat[sidx(cb0 + j, bc)] = f2bf(fmaxf(A0[j], 0.f) * bf2f(xds[0][j][c]));
                        dat[sidx(cb1 + j, bc)] = f2bf(fmaxf(A1[j], 0.f) * bf2f(xds[1][j][c]));
                    }
                });
        }

        // GEMM3 K=128 dual -> ysort
        {
            short8 a0[4], a1[4];
            #pragma unroll
            for (int kb = 0; kb < 4; ++kb) {
                a0[kb] = *(const short8*)&dat[sidx(ar0, kb * 64 + kgrp * 16)];
                a1[kb] = *(const short8*)&dat[sidx(ar1, kb * 64 + kgrp * 16)];
            }
            short8 y0[4], y1[4];
            colmm8_dual_lds<4>(a0, a1, wf3,
                [&](int c, floatx4 A0, floatx4 A1) {
                    #pragma unroll
                    for (int j = 0; j < 4; ++j) {
                        y0[j][c] = f2bf(fmaxf(A0[j] + bu[c], 0.f));
                        y1[j][c] = f2bf(fmaxf(A1[j] + bu[c], 0.f));
                    }
                });
            #pragma unroll
            for (int j = 0; j < 4; ++j) {
                int r0r = row0 + cb0 + j;
                int r1r = row0 + cb1 + j;
                if (r0r < Tcnt) *(short8*)&ysort[(size_t)r0r * 128 + ccol * 8] = y0[j];
                if (r1r < Tcnt) *(short8*)&ysort[(size_t)r1r * 128 + ccol * 8] = y1[j];
            }
        }
    }
}

// ---------------- fused layerB: CSR segment-sum + res-MLP + msg update ----------------
__launch_bounds__(256)
__global__ void layerBf_k(const short* __restrict__ ysort, const int* __restrict__ sstart,
                          const short* __restrict__ r1Wt, const float* __restrict__ r1B,
                          const short* __restrict__ r2Wt, const float* __restrict__ r2B,
                          float* __restrict__ msg) {
    __shared__ short ldsb[64 * 128];
    __shared__ float aggf[64 * 128];
    const int tid = threadIdx.x;
    const int lane = tid & 63, w = tid >> 6;
    const int row0 = blockIdx.x * 64;
    const int g16 = lane & 15;
    const int q   = lane >> 4;

    for (int it = 0; it < 16; ++it) {
        int el = it * 4 + w;
        int e = row0 + el;
        int s = sstart[e], tEnd = sstart[e + 1];
        float acc[8] = {0.f, 0.f, 0.f, 0.f, 0.f, 0.f, 0.f, 0.f};
        for (int r = s + q; r < tEnd; r += 4) {
            short8 y = *(const short8*)&ysort[(size_t)r * 128 + g16 * 8];
            #pragma unroll
            for (int c = 0; c < 8; ++c) acc[c] += bf2f(y[c]);
        }
        #pragma unroll
        for (int c = 0; c < 8; ++c) {
            acc[c] += __shfl_xor(acc[c], 16);
            acc[c] += __shfl_xor(acc[c], 32);
        }
        if (q == 0) {
            unsigned u[4];
            #pragma unroll
            for (int h = 0; h < 4; ++h) u[h] = pack2(acc[2 * h], acc[2 * h + 1]);
            *(uint4*)&ldsb[sidx(el, g16 * 16)] = make_uint4(u[0], u[1], u[2], u[3]);
            *(float4*)&aggf[el * 128 + g16 * 8]     = make_float4(acc[0], acc[1], acc[2], acc[3]);
            *(float4*)&aggf[el * 128 + g16 * 8 + 4] = make_float4(acc[4], acc[5], acc[6], acc[7]);
        }
    }
    __syncthreads();

    const int kgrp = lane >> 4, ccol = lane & 15;
    const int arow = w * 16 + ccol;
    const int cr0  = w * 16 + kgrp * 4;
    short8 a1[4];
    #pragma unroll
    for (int kb = 0; kb < 4; ++kb)
        a1[kb] = *(const short8*)&ldsb[sidx(arow, kb * 64 + kgrp * 16)];
    floatx4 o[8];
    colmm8_pf<4, 128>(a1, r1Wt + ccol * 128 + kgrp * 8, o);
    #pragma unroll
    for (int c = 0; c < 8; ++c) {
        int colg = c * 16 + ccol;
        float b1 = r1B[colg];
        #pragma unroll
        for (int j = 0; j < 4; ++j)
            ldsb[sidx(cr0 + j, 2 * colg)] = f2bf(fmaxf(o[c][j] + b1, 0.f));
    }
    short8 a2[4];
    #pragma unroll
    for (int kb = 0; kb < 4; ++kb)
        a2[kb] = *(const short8*)&ldsb[sidx(arow, kb * 64 + kgrp * 16)];
    colmm8_pf<4, 128>(a2, r2Wt + ccol * 128 + kgrp * 8, o);
    #pragma unroll
    for (int c = 0; c < 8; ++c) {
        int colg = c * 16 + ccol;
        float b2 = r2B[colg];
        #pragma unroll
        for (int j = 0; j < 4; ++j) {
            size_t ofs = (size_t)(row0 + cr0 + j) * 128 + colg;
            float ag = aggf[(cr0 + j) * 128 + ccol * 8 + c];
            msg[ofs] = msg[ofs] + ag + fmaxf(o[c][j] + b2, 0.f);
        }
    }
}

// ---------------- initial message (K=160, pad 147) ----------------
__launch_bounds__(256, 3)
__global__ void imsg_k(const float* __restrict__ af, const float* __restrict__ ef,
                       const int* __restrict__ idx_j,
                       const short* __restrict__ Wt, const float* __restrict__ bias,
                       float* __restrict__ msg) {
    __shared__ short lds[64 * 256];
    const int tid = threadIdx.x;
    const int lane = tid & 63, w = tid >> 6;
    const int row0 = blockIdx.x * 64;

    #pragma unroll
    for (int it = 0; it < 5; ++it) {
        int chunk = tid + it * 256;
        int r = chunk / 20, cg = chunk % 20;
        int row = row0 + r;
        int g = idx_j[row];
        unsigned u[4];
        #pragma unroll
        for (int h = 0; h < 4; ++h) {
            int k0 = cg * 8 + 2 * h;
            int k1 = k0 + 1;
            float f0 = (k0 < 133) ? af[(size_t)g * 133 + k0]
                     : (k0 < 147) ? ef[(size_t)row * 14 + (k0 - 133)] : 0.f;
            float f1 = (k1 < 133) ? af[(size_t)g * 133 + k1]
                     : (k1 < 147) ? ef[(size_t)row * 14 + (k1 - 133)] : 0.f;
            u[h] = pack2(f0, f1);
        }
        *(uint4*)&lds[sidxg(r, cg * 16, 256)] = make_uint4(u[0], u[1], u[2], u[3]);
    }
    __syncthreads();

    const int kgrp = lane >> 4, ccol = lane & 15;
    const int arow = w * 16 + ccol;
    const int cr0  = w * 16 + kgrp * 4;
    short8 a[5];
    #pragma unroll
    for (int kb = 0; kb < 5; ++kb)
        a[kb] = *(const short8*)&lds[sidxg(arow, kb * 64 + kgrp * 16, 256)];
    floatx4 o[8];
    colmm8_pf<5, 160>(a, Wt + ccol * 160 + kgrp * 8, o);
    #pragma unroll
    for (int c = 0; c < 8; ++c) {
        int colg = c * 16 + ccol;
        float bv = bias[colg];
        #pragma unroll
        for (int j = 0; j < 4; ++j)
            msg[(size_t)(row0 + cr0 + j) * 128 + colg] = fmaxf(o[c][j] + bv, 0.f);
    }
}

// ---------------- layerA (streaming weights) ----------------
__launch_bounds__(256, 3)
__global__ void layerA_k(const float* __restrict__ msg, const short* __restrict__ rbfe,
                         const short* __restrict__ kjWt, const float* __restrict__ kjB,
                         const short* __restrict__ rbf2Wt, const float* __restrict__ rbf2B,
                         const short* __restrict__ downWt, const float* __restrict__ downB,
                         short* __restrict__ xdown) {
    __shared__ short ldsM[64 * 128];
    __shared__ short ldsR[64 * 128];
    const int tid = threadIdx.x;
    const int lane = tid & 63, w = tid >> 6;
    const size_t row0 = (size_t)blockIdx.x * 64;
    stage64x128(msg, row0, ldsM, tid);
    stage_bf(rbfe, row0, ldsR, tid);
    __syncthreads();
    const int kgrp = lane >> 4, ccol = lane & 15;
    const int arow = w * 16 + ccol;
    const int cr0  = w * 16 + kgrp * 4;
    short8 aM[4], aR[4];
    #pragma unroll
    for (int kb = 0; kb < 4; ++kb) {
        aM[kb] = *(const short8*)&ldsM[sidx(arow, kb * 64 + kgrp * 16)];
        aR[kb] = *(const short8*)&ldsR[sidx(arow, kb * 64 + kgrp * 16)];
    }
    floatx4 oR[8], oK[8];
    colmm8_pf<4, 128>(aR, rbf2Wt + ccol * 128 + kgrp * 8, oR);
    colmm8_pf<4, 128>(aM, kjWt   + ccol * 128 + kgrp * 8, oK);
    #pragma unroll
    for (int c = 0; c < 8; ++c) {
        int colg = c * 16 + ccol;
        float rb = rbf2B[colg], kbb = kjB[colg];
        #pragma unroll
        for (int j = 0; j < 4; ++j) {
            float x = fmaxf(oK[c][j] + kbb, 0.f) * fmaxf(oR[c][j] + rb, 0.f);
            ldsM[sidx(cr0 + j, 2 * colg)] = f2bf(x);
        }
    }
    short8 aX[4];
    #pragma unroll
    for (int kb = 0; kb < 4; ++kb)
        aX[kb] = *(const short8*)&ldsM[sidx(arow, kb * 64 + kgrp * 16)];
    colmm8_pf<4, 128>(aX, downWt + ccol * 128 + kgrp * 8, oK);
    #pragma unroll
    for (int j = 0; j < 4; ++j) {
        short8 v;
        #pragma unroll
        for (int c = 0; c < 8; ++c)
            v[c] = f2bf(fmaxf(oK[c][j] + downB[c * 16 + ccol], 0.f));
        *(short8*)&xdown[(row0 + cr0 + j) * 128 + ccol * 8] = v;
    }
}

// ---------------- rbfe FUSED (rbf_h K=32 stage + K=128 GEMM, bf16 out) ----------------
__launch_bounds__(256, 3)
__global__ void rbfe_k(const float* __restrict__ rbf0, const short* __restrict__ W16,
                       const float* __restrict__ b16, const short* __restrict__ W3t,
                       const float* __restrict__ bias,
                       const int* __restrict__ idx_i, const int* __restrict__ idx_j,
                       const int* __restrict__ atype,
                       const float* __restrict__ P1, const float* __restrict__ P2,
                       short* __restrict__ out) {
    __shared__ short lds[64 * 128];
    const int tid = threadIdx.x;
    const int lane = tid & 63, w = tid >> 6;
    const int row0 = blockIdx.x * 64;
    const int kgrp = lane >> 4, ccol = lane & 15;
    const int arow = w * 16 + ccol;
    const int cr0  = w * 16 + kgrp * 4;

    {
        short8 a0;
        if (kgrp < 2) {
            int grow = row0 + arow;
            float4 r0 = *(const float4*)&rbf0[(size_t)grow * 16 + kgrp * 8];
            float4 r1 = *(const float4*)&rbf0[(size_t)grow * 16 + kgrp * 8 + 4];
            a0[0] = f2bf(r0.x); a0[1] = f2bf(r0.y); a0[2] = f2bf(r0.z); a0[3] = f2bf(r0.w);
            a0[4] = f2bf(r1.x); a0[5] = f2bf(r1.y); a0[6] = f2bf(r1.z); a0[7] = f2bf(r1.w);
        } else {
            a0 = short8{0, 0, 0, 0, 0, 0, 0, 0};
        }
        floatx4 o[8];
        colmm8_pf<1, 32>(&a0, W16 + ccol * 32 + kgrp * 8, o);
        #pragma unroll
        for (int c = 0; c < 8; ++c) {
            float bv = b16[c * 16 + ccol];
            #pragma unroll
            for (int j = 0; j < 4; ++j)
                lds[sidx(cr0 + j, 2 * (c * 16 + ccol))] = f2bf(fmaxf(o[c][j] + bv, 0.f));
        }
    }
    // band-local -> no barrier

    const float* p1p[4]; const float* p2p[4];
    #pragma unroll
    for (int j = 0; j < 4; ++j) {
        int row = row0 + cr0 + j;
        p1p[j] = P1 + (size_t)atype[idx_i[row]] * 128;
        p2p[j] = P2 + (size_t)atype[idx_j[row]] * 128;
    }
    short8 a[4];
    #pragma unroll
    for (int kb = 0; kb < 4; ++kb)
        a[kb] = *(const short8*)&lds[sidx(arow, kb * 64 + kgrp * 16)];
    floatx4 o[8];
    colmm8_pf<4, 128>(a, W3t + ccol * 128 + kgrp * 8, o);
    #pragma unroll
    for (int c = 0; c < 8; ++c) {
        int colg = c * 16 + ccol;
        float bv = bias[colg];
        #pragma unroll
        for (int j = 0; j < 4; ++j)
            out[(size_t)(row0 + cr0 + j) * 128 + colg] =
                f2bf(fmaxf(o[c][j] + bv + p1p[j][colg] + p2p[j][colg], 0.f));
    }
}

// ---------------- concat GEMM (fp32, final projection only) ----------------
__launch_bounds__(256)
__global__ void concatgemm_k(const float* __restrict__ IN1, int K1,
                             const float* __restrict__ IN2, int K2,
                             const float* __restrict__ W, const float* __restrict__ bias,
                             float* __restrict__ Y, int M) {
    __shared__ float xs[96 * 68];
    const int tid = threadIdx.x;
    const int row0 = blockIdx.x * 64;
    const int col8 = (tid & 15) * 8;
    const int r0 = (tid >> 4) * 4;
    const int K = K1 + K2;

    float acc[4][8];
    #pragma unroll
    for (int r = 0; r < 4; ++r)
        #pragma unroll
        for (int c = 0; c < 8; ++c) acc[r][c] = 0.f;

    for (int kb = 0; kb < K; kb += 96) {
        int kc = (K - kb < 96) ? (K - kb) : 96;
        __syncthreads();
        for (int idx = tid; idx < 64 * 96; idx += 256) {
            int r = idx / 96, kl = idx % 96;
            if (kl < kc) {
                int row = row0 + r;
                float v = 0.f;
                if (row < M) {
                    int kg = kb + kl;
                    v = (kg < K1) ? IN1[(size_t)row * K1 + kg]
                                  : IN2[(size_t)row * K2 + (kg - K1)];
                }
                xs[kl * 68 + r] = v;
            }
        }
        __syncthreads();
        for (int k = 0; k < kc; ++k) {
            float4 xv = *(const float4*)&xs[k * 68 + r0];
            const float* wr = &W[(size_t)(kb + k) * 128 + col8];
            float4 w0 = *(const float4*)wr;
            float4 w1 = *(const float4*)(wr + 4);
            float xr[4] = {xv.x, xv.y, xv.z, xv.w};
            float wc[8] = {w0.x, w0.y, w0.z, w0.w, w1.x, w1.y, w1.z, w1.w};
            #pragma unroll
            for (int r = 0; r < 4; ++r)
                #pragma unroll
                for (int c = 0; c < 8; ++c)
                    acc[r][c] = fmaf(xr[r], wc[c], acc[r][c]);
        }
    }

    float4 b0 = *(const float4*)&bias[col8];
    float4 b1 = *(const float4*)&bias[col8 + 4];
    float bb[8] = {b0.x, b0.y, b0.z, b0.w, b1.x, b1.y, b1.z, b1.w};
    #pragma unroll
    for (int r = 0; r < 4; ++r) {
        int row = row0 + r0 + r;
        if (row >= M) continue;
        float v[8];
        #pragma unroll
        for (int c = 0; c < 8; ++c) v[c] = fmaxf(acc[r][c] + bb[c], 0.f);
        *(float4*)&Y[(size_t)row * 128 + col8]     = make_float4(v[0], v[1], v[2], v[3]);
        *(float4*)&Y[(size_t)row * 128 + col8 + 4] = make_float4(v[4], v[5], v[6], v[7]);
    }
}

// ---------------- host ----------------

extern "C" void kernel_launch(void* const* d_in, const int* in_sizes, int n_in,
                              void* d_out, int out_size, void* d_ws, size_t ws_size,
                              hipStream_t stream) {
    const float* atom_feature = (const float*)d_in[0];
    const float* edge_feature = (const float*)d_in[1];
    const float* dist         = (const float*)d_in[2];
    const float* angle        = (const float*)d_in[3];
    const float* W_i1_w       = (const float*)d_in[4];
    const float* W_i1_b       = (const float*)d_in[5];
    const float* emb_table    = (const float*)d_in[6];
    const float* lin_rbf_w    = (const float*)d_in[7];
    const float* lin_rbf_b    = (const float*)d_in[8];
    const float* lin_emb_w    = (const float*)d_in[9];
    const float* lin_emb_b    = (const float*)d_in[10];
    const float* bessel_freq  = (const float*)d_in[11];
    const float* L_rbf2_w     = (const float*)d_in[12];
    const float* L_rbf2_b     = (const float*)d_in[13];
    const float* L_kj_w       = (const float*)d_in[14];
    const float* L_kj_b       = (const float*)d_in[15];
    const float* L_sbf1_w     = (const float*)d_in[16];
    const float* L_sbf2_w     = (const float*)d_in[17];
    const float* L_down_w     = (const float*)d_in[18];
    const float* L_down_b     = (const float*)d_in[19];
    const float* L_up_w       = (const float*)d_in[20];
    const float* L_up_b       = (const float*)d_in[21];
    const float* L_res1_w     = (const float*)d_in[22];
    const float* L_res1_b     = (const float*)d_in[23];
    const float* L_res2_w     = (const float*)d_in[24];
    const float* L_res2_b     = (const float*)d_in[25];
    const float* W_o_w        = (const float*)d_in[26];
    const float* W_o_b        = (const float*)d_in[27];
    const int* idx_i          = (const int*)d_in[28];
    const int* idx_j          = (const int*)d_in[29];
    const int* idx_kj         = (const int*)d_in[30];
    const int* ib_eid         = (const int*)d_in[32];
    const int* ib_atom        = (const int*)d_in[33];

    float* ws = (float*)d_ws;
    size_t off = 0;
    auto take = [&](size_t n) { float* p = ws + off; off += n; return p; };
    float* msg    = take((size_t)Ecnt * 128);
    short* rbfe   = (short*)take((size_t)Ecnt * 64);
    short* sxd    = (short*)take((size_t)Ecnt * 64);
    short* ysort  = (short*)take((size_t)Tcnt * 64);
    float* rbf0b  = take((size_t)Ecnt * 16);
    float* P1     = take(100 * 128);
    float* P2     = take(100 * 128);
    int*   atyp   = (int*)take(Ncnt);
    int*   cnts   = (int*)take(Ecnt);
    int*   sstart = (int*)take(Ecnt + 1);
    int*   cur    = (int*)take(Ecnt);
    int*   btot   = (int*)take(512);
    int*   boff   = (int*)take(512);
    int*   eids   = (int*)take(Tcnt);
    float* angs   = take(Tcnt);
    int*   sstartA= (int*)take(Ncnt + 1);
    int*   eidsA  = (int*)take(Ecnt);
    short* wts    = (short*)take(160100);

    if (off * sizeof(float) > ws_size) {
        sentinel_k<<<1, 256, 0, stream>>>((float*)d_out, (float)ws_size);
        return;
    }

    float* atomm = (float*)ysort;   // alias: ysort dead after last layerBf

    const int GE  = Ecnt / 64;
    const int GN  = (Ncnt + 63) / 64;
    const int NBE = (Ecnt + 255) / 256;
    const int NBT = (Tcnt + 255) / 256;
    const int NBA = (Ncnt + 255) / 256;

    atype_k<<<(Ncnt + 255) / 256, 256, 0, stream>>>(atom_feature, atyp);
    pemb_k<<<100, 128, 0, stream>>>(emb_table, lin_emb_w, P1, P2);
    rbf0_k<<<NBE, 256, 0, stream>>>(dist, bessel_freq, rbf0b);

    // --- edge CSR sort (triplets by target edge) ---
    hipMemsetAsync(cnts, 0, (size_t)Ecnt * sizeof(int), stream);
    hist_k<<<NBT, 256, 0, stream>>>(idx_kj, cnts, Tcnt);
    scan1_k<<<NBE, 256, 0, stream>>>(cnts, btot, Ecnt);
    scan2_k<<<1, 512, 0, stream>>>(btot, boff, NBE);
    scan3_k<<<NBE, 256, 0, stream>>>(cnts, boff, sstart, cur, Ecnt, Tcnt);
    perm_k<<<NBT, 256, 0, stream>>>(idx_kj, angle, cur, eids, angs);

    // --- atom CSR sort (incoming edges by atom) ---
    hipMemsetAsync(cnts, 0, (size_t)Ncnt * sizeof(int), stream);
    hist_k<<<NBE, 256, 0, stream>>>(ib_atom, cnts, Ecnt);
    scan1_k<<<NBA, 256, 0, stream>>>(cnts, btot, Ncnt);
    scan2_k<<<1, 512, 0, stream>>>(btot, boff, NBA);
    scan3_k<<<NBA, 256, 0, stream>>>(cnts, boff, sstartA, cur, Ncnt, Ecnt);
    permA_k<<<NBE, 256, 0, stream>>>(ib_atom, ib_eid, cur, eidsA);

    // --- weight prep ---
    short* p = wts;
    short* wt1[2]; short* wt2[2]; short* wt3[2];
    short* wkj[2]; short* wr2f[2]; short* wdn[2]; short* wr1[2]; short* wr2[2];
    for (int l = 0; l < 2; ++l) {
        wt1[l] = p; p += 96 * 128;
        wt2[l] = p; p += 128 * 128;
        wt3[l] = p; p += 128 * 128;
        wkj[l] = p; p += 128 * 128;
        wr2f[l] = p; p += 128 * 128;
        wdn[l] = p; p += 128 * 128;
        wr1[l] = p; p += 128 * 128;
        wr2[l] = p; p += 128 * 128;
    }
    short* wemb3 = p; p += 128 * 128;
    short* wi1t  = p; p += 128 * 160;
    short* w16   = p; p += 128 * 32;

    WPack wp;
    int m = 0;
    for (int l = 0; l < 2; ++l) {
        wp.src[m] = L_kj_w   + (size_t)l * 128 * 128; wp.dst[m] = wkj[l];  wp.perm[m++] = 0;
        wp.src[m] = L_rbf2_w + (size_t)l * 128 * 128; wp.dst[m] = wr2f[l]; wp.perm[m++] = 0;
        wp.src[m] = L_down_w + (size_t)l * 128 * 128; wp.dst[m] = wdn[l];  wp.perm[m++] = 0;
        wp.src[m] = L_res1_w + (size_t)l * 128 * 128; wp.dst[m] = wr1[l];  wp.perm[m++] = 1;
        wp.src[m] = L_res2_w + (size_t)l * 128 * 128; wp.dst[m] = wr2[l];  wp.perm[m++] = 0;
    }
    wp.src[m] = lin_emb_w + 256 * 128; wp.dst[m] = wemb3; wp.perm[m++] = 0;   // 11
    transmany_k<<<11 * 64, 256, 0, stream>>>(wp);

    FPack fp;
    m = 0;
    for (int l = 0; l < 2; ++l) {
        fp.src[m] = L_sbf1_w + (size_t)l * 96 * 128;  fp.dst[m] = wt1[l]; fp.nkb[m++] = 3;
        fp.src[m] = L_sbf2_w + (size_t)l * 128 * 128; fp.dst[m] = wt2[l]; fp.nkb[m++] = 4;
        fp.src[m] = L_up_w   + (size_t)l * 128 * 128; fp.dst[m] = wt3[l]; fp.nkb[m++] = 4;
    }
    transfragall_k<<<6 * 64, 256, 0, stream>>>(fp);
    transWi1_k<<<(128 * 160 + 255) / 256, 256, 0, stream>>>(W_i1_w, wi1t);
    transW16_k<<<16, 256, 0, stream>>>(lin_rbf_w, w16);

    // --- initial message + fused rbf_e ---
    imsg_k<<<GE, 256, 0, stream>>>(atom_feature, edge_feature, idx_j, wi1t, W_i1_b, msg);
    rbfe_k<<<GE, 256, 0, stream>>>(rbf0b, w16, lin_rbf_b, wemb3, lin_emb_b,
                                   idx_i, idx_j, atyp, P1, P2, rbfe);

    for (int l = 0; l < 2; ++l) {
        layerA_k<<<GE, 256, 0, stream>>>(msg, rbfe,
                                         wkj[l], L_kj_b + (size_t)l * 128,
                                         wr2f[l], L_rbf2_b + (size_t)l * 128,
                                         wdn[l], L_down_b + (size_t)l * 128, sxd);
        triplet_mfma_k<<<512, 512, 0, stream>>>(angs, eids, rbf0b,
                                                wt1[l], wt2[l], wt3[l],
                                                L_up_b + (size_t)l * 128, sxd, ysort);
        layerBf_k<<<GE, 256, 0, stream>>>(ysort, sstart,
                                          wr1[l], L_res1_b + (size_t)l * 128,
                                          wr2[l], L_res2_b + (size_t)l * 128, msg);
    }

    // atom aggregation (CSR, no atomics) + final projection
    atomsum_k<<<(Ncnt * 128) / 256, 256, 0, stream>>>(msg, eidsA, sstartA, atomm);
    concatgemm_k<<<GN, 256, 0, stream>>>(atom_feature, 133, atomm, 128,
                                         W_o_w, W_o_b, (float*)d_out, Ncnt);
}

// Round 15
// 862.681 us; speedup vs baseline: 1.5496x; 1.1413x over previous
//
#include <hip/hip_runtime.h>
#include <hip/hip_bf16.h>

#define Ecnt 120000
#define Ncnt 15000
#define Tcnt 500000
#define NT256 ((Tcnt + 255) / 256)

typedef __attribute__((ext_vector_type(8))) short short8;
typedef __attribute__((ext_vector_type(4))) float floatx4;

__device__ __forceinline__ floatx4 mfma16(short8 a, short8 b, floatx4 c) {
    return __builtin_amdgcn_mfma_f32_16x16x32_bf16(a, b, c, 0, 0, 0);
}

__device__ __forceinline__ short f2bf(float f) {
    __hip_bfloat16 b = __float2bfloat16(f);
    short s;
    __builtin_memcpy(&s, &b, 2);
    return s;
}

__device__ __forceinline__ float bf2f(short s) {
    unsigned u = ((unsigned)(unsigned short)s) << 16;
    float f;
    __builtin_memcpy(&f, &u, 4);
    return f;
}

__device__ __forceinline__ unsigned pack2(float x, float y) {
    return (unsigned)(unsigned short)f2bf(x) | ((unsigned)(unsigned short)f2bf(y) << 16);
}

// bf16 MFMA tile swizzle: byte-col XOR (row&15)<<4, BOTH sides.
__device__ __forceinline__ int sidx(int row, int bc) {
    return row * 128 + (((bc) ^ ((row & 15) << 4)) >> 1);
}
__device__ __forceinline__ int sidxg(int row, int bc, int ldshorts) {
    return row * ldshorts + (((bc) ^ ((row & 15) << 4)) >> 1);
}

__device__ __forceinline__ void stage64x128(const float* __restrict__ src, size_t row0,
                                            short* __restrict__ lds, int tid) {
    #pragma unroll
    for (int it = 0; it < 8; ++it) {
        int chunk = tid + it * 256;
        int r = chunk >> 5, c4 = chunk & 31;
        float4 v = *(const float4*)&src[(row0 + r) * 128 + c4 * 4];
        *(uint2*)&lds[sidx(r, c4 * 8)] = make_uint2(pack2(v.x, v.y), pack2(v.z, v.w));
    }
}

__device__ __forceinline__ void stage_bf(const short* __restrict__ src, size_t row0,
                                         short* __restrict__ lds, int tid) {
    #pragma unroll
    for (int it = 0; it < 4; ++it) {
        int chunk = tid + it * 256;
        int r = chunk >> 4, cg = chunk & 15;
        uint4 v = *(const uint4*)&src[(row0 + r) * 128 + cg * 8];
        *(uint4*)&lds[sidx(r, cg * 16)] = v;
    }
}

// global-weight 8-col GEMM with 2-deep prefetch
template<int NKB, int K>
__device__ __forceinline__ void colmm8_pf(const short8 a[NKB], const short* __restrict__ wcol,
                                          floatx4 out[8]) {
    short8 w[2][NKB];
    #pragma unroll
    for (int kb = 0; kb < NKB; ++kb) w[0][kb] = *(const short8*)(wcol + kb * 32);
    #pragma unroll
    for (int kb = 0; kb < NKB; ++kb) w[1][kb] = *(const short8*)(wcol + 16 * K + kb * 32);
    #pragma unroll
    for (int c = 0; c < 8; ++c) {
        floatx4 acc = {0.f, 0.f, 0.f, 0.f};
        #pragma unroll
        for (int kb = 0; kb < NKB; ++kb) acc = mfma16(a[kb], w[c & 1][kb], acc);
        out[c] = acc;
        if (c + 2 < 8) {
            #pragma unroll
            for (int kb = 0; kb < NKB; ++kb)
                w[c & 1][kb] = *(const short8*)(wcol + (size_t)(c + 2) * 16 * K + kb * 32);
        }
    }
}

// global-weight 4-col GEMM with 2-deep prefetch (layerBf col-split)
template<int NKB, int K>
__device__ __forceinline__ void colmm4_pf(const short8 a[NKB], const short* __restrict__ wcol,
                                          floatx4 out[4]) {
    short8 w[2][NKB];
    #pragma unroll
    for (int kb = 0; kb < NKB; ++kb) w[0][kb] = *(const short8*)(wcol + kb * 32);
    #pragma unroll
    for (int kb = 0; kb < NKB; ++kb) w[1][kb] = *(const short8*)(wcol + 16 * K + kb * 32);
    #pragma unroll
    for (int c = 0; c < 4; ++c) {
        floatx4 acc = {0.f, 0.f, 0.f, 0.f};
        #pragma unroll
        for (int kb = 0; kb < NKB; ++kb) acc = mfma16(a[kb], w[c & 1][kb], acc);
        out[c] = acc;
        if (c + 2 < 4) {
            #pragma unroll
            for (int kb = 0; kb < NKB; ++kb)
                w[c & 1][kb] = *(const short8*)(wcol + (size_t)(c + 2) * 16 * K + kb * 32);
        }
    }
}

// LDS fragment-major 8-col GEMM, single row-group
template<int NKB>
__device__ __forceinline__ void colmm8_lds(const short8 a[NKB], const short* __restrict__ wf,
                                           floatx4 out[8]) {
    short8 w[2][NKB];
    #pragma unroll
    for (int kb = 0; kb < NKB; ++kb) w[0][kb] = *(const short8*)(wf + kb * 512);
    #pragma unroll
    for (int kb = 0; kb < NKB; ++kb) w[1][kb] = *(const short8*)(wf + (NKB + kb) * 512);
    #pragma unroll
    for (int c = 0; c < 8; ++c) {
        floatx4 acc = {0.f, 0.f, 0.f, 0.f};
        #pragma unroll
        for (int kb = 0; kb < NKB; ++kb) acc = mfma16(a[kb], w[c & 1][kb], acc);
        out[c] = acc;
        if (c + 2 < 8) {
            #pragma unroll
            for (int kb = 0; kb < NKB; ++kb)
                w[c & 1][kb] = *(const short8*)(wf + ((c + 2) * NKB + kb) * 512);
        }
    }
}

// LDS fragment-major 8-col GEMM, DUAL row-group
template<int NKB, typename Epi>
__device__ __forceinline__ void colmm8_dual_lds(const short8 a0[NKB], const short8 a1[NKB],
                                                const short* __restrict__ wf, Epi epi) {
    short8 w[2][NKB];
    #pragma unroll
    for (int kb = 0; kb < NKB; ++kb) w[0][kb] = *(const short8*)(wf + kb * 512);
    #pragma unroll
    for (int kb = 0; kb < NKB; ++kb) w[1][kb] = *(const short8*)(wf + (NKB + kb) * 512);
    #pragma unroll
    for (int c = 0; c < 8; ++c) {
        floatx4 acc0 = {0.f, 0.f, 0.f, 0.f};
        floatx4 acc1 = {0.f, 0.f, 0.f, 0.f};
        #pragma unroll
        for (int kb = 0; kb < NKB; ++kb) {
            acc0 = mfma16(a0[kb], w[c & 1][kb], acc0);
            acc1 = mfma16(a1[kb], w[c & 1][kb], acc1);
        }
        epi(c, acc0, acc1);
        if (c + 2 < 8) {
            #pragma unroll
            for (int kb = 0; kb < NKB; ++kb)
                w[c & 1][kb] = *(const short8*)(wf + ((c + 2) * NKB + kb) * 512);
        }
    }
}

// ---------------- small kernels ----------------

__launch_bounds__(256)
__global__ void sentinel_k(float* o, float v) { o[0] = v; }

__launch_bounds__(256)
__global__ void atype_k(const float* __restrict__ af, int* __restrict__ atype) {
    int n = blockIdx.x * 256 + threadIdx.x;
    if (n >= Ncnt) return;
    const float* r = af + (size_t)n * 133;
    int best = 0; float bv = r[0];
    for (int k = 1; k < 100; ++k) { float v = r[k]; if (v > bv) { bv = v; best = k; } }
    atype[n] = best;
}

__launch_bounds__(128)
__global__ void pemb_k(const float* __restrict__ emb, const float* __restrict__ W,
                       float* __restrict__ P1, float* __restrict__ P2) {
    int r = blockIdx.x, c = threadIdx.x;
    __shared__ float er[128];
    er[c] = emb[r * 128 + c];
    __syncthreads();
    float a1 = 0.f, a2 = 0.f;
    for (int k = 0; k < 128; ++k) {
        float e = er[k];
        a1 = fmaf(e, W[k * 128 + c], a1);
        a2 = fmaf(e, W[(128 + k) * 128 + c], a2);
    }
    P1[r * 128 + c] = a1;
    P2[r * 128 + c] = a2;
}

__launch_bounds__(256)
__global__ void rbf0_k(const float* __restrict__ dist, const float* __restrict__ freq,
                       float* __restrict__ rbf0) {
    int e = blockIdx.x * 256 + threadIdx.x;
    if (e >= Ecnt) return;
    float x = dist[e] * 0.125f;
    float x2 = x * x;
    float x5 = x2 * x2 * x;
    float env = 1.f / x - 28.f * x5 + 48.f * x5 * x - 21.f * x5 * x2;
    if (!(x < 1.f)) env = 0.f;
    #pragma unroll
    for (int r = 0; r < 16; ++r)
        rbf0[(size_t)e * 16 + r] = env * sinf(freq[r] * x);
}

__launch_bounds__(256)
__global__ void atomsum_k(const float* __restrict__ msg, const int* __restrict__ eidsA,
                          const int* __restrict__ sstartA, float* __restrict__ am) {
    int gid = blockIdx.x * 256 + threadIdx.x;
    int a = gid >> 7, c = gid & 127;
    int s = sstartA[a], e = sstartA[a + 1];
    float acc = 0.f;
    for (int r = s; r < e; ++r)
        acc += msg[(size_t)eidsA[r] * 128 + c];
    am[(size_t)a * 128 + c] = acc;
}

// T[t][c] = W_o[t][c] + b[c]  (one-hot fold, exact)
__launch_bounds__(256)
__global__ void tprep_k(const float* __restrict__ W, const float* __restrict__ b,
                        float* __restrict__ T) {
    int i = blockIdx.x * 256 + threadIdx.x;
    if (i >= 100 * 128) return;
    T[i] = W[i] + b[i & 127];
}

// ---------------- sorting (generic CSR) ----------------

__launch_bounds__(256)
__global__ void hist_k(const int* __restrict__ idx, int* __restrict__ cnt, int n) {
    int t = blockIdx.x * 256 + threadIdx.x;
    if (t < n) atomicAdd(&cnt[idx[t]], 1);
}

__launch_bounds__(256)
__global__ void scan1_k(int* __restrict__ cnt, int* __restrict__ btot, int n) {
    __shared__ int s[256];
    int t = threadIdx.x, i = blockIdx.x * 256 + t;
    int v = (i < n) ? cnt[i] : 0;
    s[t] = v;
    #pragma unroll
    for (int off = 1; off < 256; off <<= 1) {
        __syncthreads();
        int nv = (t >= off) ? s[t - off] + s[t] : s[t];
        __syncthreads();
        s[t] = nv;
    }
    if (i < n) cnt[i] = s[t] - v;
    if (t == 255) btot[blockIdx.x] = s[255];
}

__launch_bounds__(512)
__global__ void scan2_k(const int* __restrict__ btot, int* __restrict__ boff, int nb) {
    __shared__ int s[512];
    int t = threadIdx.x;
    int v = (t < nb) ? btot[t] : 0;
    s[t] = v;
    #pragma unroll
    for (int off = 1; off < 512; off <<= 1) {
        __syncthreads();
        int nv = (t >= off) ? s[t - off] + s[t] : s[t];
        __syncthreads();
        s[t] = nv;
    }
    if (t < nb) boff[t] = s[t] - v;
}

__launch_bounds__(256)
__global__ void scan3_k(const int* __restrict__ basep, const int* __restrict__ boff,
                        int* __restrict__ sstart, int* __restrict__ cur, int n, int total) {
    int i = blockIdx.x * 256 + threadIdx.x;
    if (i < n) {
        int v = basep[i] + boff[i >> 8];
        sstart[i] = v;
        cur[i] = v;
    }
    if (i == 0) sstart[n] = total;
}

__launch_bounds__(256)
__global__ void perm_k(const int* __restrict__ idx, const float* __restrict__ angle,
                       int* __restrict__ cur, int* __restrict__ eids,
                       float* __restrict__ angs) {
    int t = blockIdx.x * 256 + threadIdx.x;
    if (t >= Tcnt) return;
    int e = idx[t];
    int p = atomicAdd(&cur[e], 1);
    eids[p] = e;
    angs[p] = angle[t];
}

__launch_bounds__(256)
__global__ void permA_k(const int* __restrict__ aid, const int* __restrict__ eid,
                        int* __restrict__ cur, int* __restrict__ eidsA) {
    int t = blockIdx.x * 256 + threadIdx.x;
    if (t >= Ecnt) return;
    int p = atomicAdd(&cur[aid[t]], 1);
    eidsA[p] = eid[t];
}

// ---------------- weight conversion (batched) ----------------

struct WPack {
    const float* src[11];
    short* dst[11];
    int perm[11];
};
__launch_bounds__(256)
__global__ void transmany_k(WPack p) {
    int m = blockIdx.x >> 6;
    int i = ((blockIdx.x & 63) << 8) + threadIdx.x;
    int c = i & 127, pi = i >> 7;
    int k = p.perm[m] ? ((pi & 7) * 16 + (pi >> 3)) : pi;
    p.dst[m][c * 128 + pi] = f2bf(p.src[m][(size_t)k * 128 + c]);
}

struct FPack {
    const float* src[6];
    short* dst[6];
    int nkb[6];
};
__launch_bounds__(256)
__global__ void transfragall_k(FPack p) {
    int m = blockIdx.x >> 6;
    int i = ((blockIdx.x & 63) << 8) + threadIdx.x;
    int NKB = p.nkb[m];
    if (i >= NKB * 4096) return;
    int e = i & 7;
    int lane = (i >> 3) & 63;
    int ckb = i >> 9;
    int c = ckb / NKB, kb = ckb - c * NKB;
    int n = c * 16 + (lane & 15);
    int k = kb * 32 + (lane >> 4) * 8 + e;
    p.dst[m][i] = f2bf(p.src[m][(size_t)k * 128 + n]);
}

__launch_bounds__(256)
__global__ void transWi1_k(const float* __restrict__ W, short* __restrict__ out) {
    int i = blockIdx.x * 256 + threadIdx.x;
    if (i >= 128 * 160) return;
    int c = i / 160, k = i % 160;
    out[i] = (k < 147) ? f2bf(W[k * 128 + c]) : (short)0;
}

__launch_bounds__(256)
__global__ void transW16_k(const float* __restrict__ W, short* __restrict__ out) {
    int i = blockIdx.x * 256 + threadIdx.x;
    if (i >= 128 * 32) return;
    int c = i >> 5, k = i & 31;
    out[i] = (k < 16) ? f2bf(W[k * 128 + c]) : (short)0;
}

// ---------------- triplet: 512 thr, 256-row tile, LDS weights, DUAL row-group ----------------
__launch_bounds__(512)
__global__ void triplet_mfma_k(const float* __restrict__ angs, const int* __restrict__ eids,
                               const float* __restrict__ rbf0,
                               const short* __restrict__ W1f, const short* __restrict__ W2f,
                               const short* __restrict__ W3f, const float* __restrict__ upB,
                               const short* __restrict__ xdown, short* __restrict__ ysort) {
    __shared__ short wl[77824];          // 152 KB
    short* w1  = wl;
    short* w2  = wl + 12288;
    short* w3  = wl + 28672;
    short* dat = wl + 45056;

    const int tid = threadIdx.x;
    const int lane = tid & 63;
    const int w = tid >> 6;
    const int kgrp = lane >> 4;
    const int ccol = lane & 15;
    const int ar0 = w * 32 + ccol;
    const int ar1 = w * 32 + 16 + ccol;
    const int cb0 = w * 32 + kgrp * 4;
    const int cb1 = w * 32 + 16 + kgrp * 4;

    for (int i = tid; i < 1536; i += 512)
        *(uint4*)&w1[i * 8] = *(const uint4*)&W1f[i * 8];
    for (int i = tid; i < 2048; i += 512)
        *(uint4*)&w2[i * 8] = *(const uint4*)&W2f[i * 8];
    for (int i = tid; i < 2048; i += 512)
        *(uint4*)&w3[i * 8] = *(const uint4*)&W3f[i * 8];
    __syncthreads();

    float bu[8];
    #pragma unroll
    for (int c = 0; c < 8; ++c) bu[c] = upB[c * 16 + ccol];
    const short* wf1 = w1 + lane * 8;
    const short* wf2 = w2 + lane * 8;
    const short* wf3 = w3 + lane * 8;

    for (int tile = blockIdx.x; tile < NT256; tile += gridDim.x) {
        const int row0 = tile * 256;

        {
            int r = tid >> 1, h = tid & 1;
            int srow = row0 + r;
            float cb[6], rb[16];
            if (srow < Tcnt) {
                float ang = angs[srow];
                int ge = eids[srow];
                float c1 = cosf(ang);
                cb[0] = 1.f; cb[1] = c1;
                #pragma unroll
                for (int a = 2; a < 6; ++a) cb[a] = 2.f * c1 * cb[a - 1] - cb[a - 2];
                #pragma unroll
                for (int i4 = 0; i4 < 4; ++i4) {
                    float4 r4 = *(const float4*)&rbf0[(size_t)ge * 16 + i4 * 4];
                    rb[i4*4+0] = r4.x; rb[i4*4+1] = r4.y; rb[i4*4+2] = r4.z; rb[i4*4+3] = r4.w;
                }
            } else {
                #pragma unroll
                for (int a = 0; a < 6; ++a) cb[a] = 0.f;
                #pragma unroll
                for (int q = 0; q < 16; ++q) rb[q] = 0.f;
            }
            #pragma unroll
            for (int m = 0; m < 24; ++m) {
                int v0 = h * 48 + 2 * m;
                *(unsigned*)&dat[sidx(r, 2 * v0)] =
                    pack2(cb[v0 >> 4] * rb[v0 & 15], cb[(v0 + 1) >> 4] * rb[(v0 + 1) & 15]);
            }
        }

        short8 xds[2][4];
        #pragma unroll
        for (int g = 0; g < 2; ++g)
            #pragma unroll
            for (int j = 0; j < 4; ++j) {
                int sr = row0 + (g ? cb1 : cb0) + j;
                if (sr < Tcnt) {
                    int e = eids[sr];
                    xds[g][j] = *(const short8*)&xdown[(size_t)e * 128 + ccol * 8];
                } else {
                    xds[g][j] = short8{0, 0, 0, 0, 0, 0, 0, 0};
                }
            }

        // GEMM1 K=96 dual
        {
            short8 a0[3], a1[3];
            #pragma unroll
            for (int kb = 0; kb < 3; ++kb) {
                a0[kb] = *(const short8*)&dat[sidx(ar0, kb * 64 + kgrp * 16)];
                a1[kb] = *(const short8*)&dat[sidx(ar1, kb * 64 + kgrp * 16)];
            }
            colmm8_dual_lds<3>(a0, a1, wf1,
                [&](int c, floatx4 A0, floatx4 A1) {
                    int bc = 2 * (c * 16 + ccol);
                    #pragma unroll
                    for (int j = 0; j < 4; ++j) {
                        dat[sidx(cb0 + j, bc)] = f2bf(fmaxf(A0[j], 0.f));
                        dat[sidx(cb1 + j, bc)] = f2bf(fmaxf(A1[j], 0.f));
                    }
                });
        }

        // GEMM2 K=128 dual (* xd)
        {
            short8 a0[4], a1[4];
            #pragma unroll
            for (int kb = 0; kb < 4; ++kb) {
                a0[kb] = *(const short8*)&dat[sidx(ar0, kb * 64 + kgrp * 16)];
                a1[kb] = *(const short8*)&dat[sidx(ar1, kb * 64 + kgrp * 16)];
            }
            colmm8_dual_lds<4>(a0, a1, wf2,
                [&](int c, floatx4 A0, floatx4 A1) {
                    int bc = 2 * (c * 16 + ccol);
                    #pragma unroll
                    for (int j = 0; j < 4; ++j) {
                        dat[sidx(cb0 + j, bc)] = f2bf(fmaxf(A0[j], 0.f) * bf2f(xds[0][j][c]));
                        dat[sidx(cb1 + j, bc)] = f2bf(fmaxf(A1[j], 0.f) * bf2f(xds[1][j][c]));
                    }
                });
        }

        // GEMM3 K=128 dual -> ysort
        {
            short8 a0[4], a1[4];
            #pragma unroll
            for (int kb = 0; kb < 4; ++kb) {
                a0[kb] = *(const short8*)&dat[sidx(ar0, kb * 64 + kgrp * 16)];
                a1[kb] = *(const short8*)&dat[sidx(ar1, kb * 64 + kgrp * 16)];
            }
            short8 y0[4], y1[4];
            colmm8_dual_lds<4>(a0, a1, wf3,
                [&](int c, floatx4 A0, floatx4 A1) {
                    #pragma unroll
                    for (int j = 0; j < 4; ++j) {
                        y0[j][c] = f2bf(fmaxf(A0[j] + bu[c], 0.f));
                        y1[j][c] = f2bf(fmaxf(A1[j] + bu[c], 0.f));
                    }
                });
            #pragma unroll
            for (int j = 0; j < 4; ++j) {
                int r0r = row0 + cb0 + j;
                int r1r = row0 + cb1 + j;
                if (r0r < Tcnt) *(short8*)&ysort[(size_t)r0r * 128 + ccol * 8] = y0[j];
                if (r1r < Tcnt) *(short8*)&ysort[(size_t)r1r * 128 + ccol * 8] = y1[j];
            }
        }
    }
}

// ---------------- fused layerB, 512 thr: CSR segment-sum (8 waves) + col-split res-MLP ----------------
__launch_bounds__(512)
__global__ void layerBf_k(const short* __restrict__ ysort, const int* __restrict__ sstart,
                          const short* __restrict__ r1Wt, const float* __restrict__ r1B,
                          const short* __restrict__ r2Wt, const float* __restrict__ r2B,
                          float* __restrict__ msg) {
    __shared__ short ldsb[64 * 128];   // 16 KB
    __shared__ float aggf[64 * 128];   // 32 KB
    const int tid = threadIdx.x;
    const int lane = tid & 63, w = tid >> 6;   // w 0..7
    const int row0 = blockIdx.x * 64;
    const int g16 = lane & 15;
    const int q   = lane >> 4;

    // phase 1: segment sums, 8 waves x 8 edges
    for (int it = 0; it < 8; ++it) {
        int el = it * 8 + w;
        int e = row0 + el;
        int s = sstart[e], tEnd = sstart[e + 1];
        float acc[8] = {0.f, 0.f, 0.f, 0.f, 0.f, 0.f, 0.f, 0.f};
        for (int r = s + q; r < tEnd; r += 4) {
            short8 y = *(const short8*)&ysort[(size_t)r * 128 + g16 * 8];
            #pragma unroll
            for (int c = 0; c < 8; ++c) acc[c] += bf2f(y[c]);
        }
        #pragma unroll
        for (int c = 0; c < 8; ++c) {
            acc[c] += __shfl_xor(acc[c], 16);
            acc[c] += __shfl_xor(acc[c], 32);
        }
        if (q == 0) {
            unsigned u[4];
            #pragma unroll
            for (int h = 0; h < 4; ++h) u[h] = pack2(acc[2 * h], acc[2 * h + 1]);
            *(uint4*)&ldsb[sidx(el, g16 * 16)] = make_uint4(u[0], u[1], u[2], u[3]);
            *(float4*)&aggf[el * 128 + g16 * 8]     = make_float4(acc[0], acc[1], acc[2], acc[3]);
            *(float4*)&aggf[el * 128 + g16 * 8 + 4] = make_float4(acc[4], acc[5], acc[6], acc[7]);
        }
    }
    __syncthreads();

    // GEMM phase: wave pair wp owns rows [wp*16, wp*16+16); col half h owns c-tiles h*4..h*4+3.
    const int kgrp = lane >> 4, ccol = lane & 15;
    const int wp = w >> 1, h = w & 1;
    const int arow = wp * 16 + ccol;
    const int cr0  = wp * 16 + kgrp * 4;

    short8 a1[4];
    #pragma unroll
    for (int kb = 0; kb < 4; ++kb)
        a1[kb] = *(const short8*)&ldsb[sidx(arow, kb * 64 + kgrp * 16)];
    __syncthreads();   // all a1 frags loaded before anyone overwrites ldsb

    floatx4 o[4];
    colmm4_pf<4, 128>(a1, r1Wt + (size_t)(h * 64 + ccol) * 128 + kgrp * 8, o);
    #pragma unroll
    for (int cc = 0; cc < 4; ++cc) {
        int colg = (h * 4 + cc) * 16 + ccol;
        float b1 = r1B[colg];
        #pragma unroll
        for (int j = 0; j < 4; ++j)
            ldsb[sidx(cr0 + j, 2 * colg)] = f2bf(fmaxf(o[cc][j] + b1, 0.f));
    }
    __syncthreads();   // relu1 fully written before cross-col a2 reads

    short8 a2[4];
    #pragma unroll
    for (int kb = 0; kb < 4; ++kb)
        a2[kb] = *(const short8*)&ldsb[sidx(arow, kb * 64 + kgrp * 16)];
    colmm4_pf<4, 128>(a2, r2Wt + (size_t)(h * 64 + ccol) * 128 + kgrp * 8, o);
    #pragma unroll
    for (int cc = 0; cc < 4; ++cc) {
        int colg = (h * 4 + cc) * 16 + ccol;
        float b2 = r2B[colg];
        #pragma unroll
        for (int j = 0; j < 4; ++j) {
            size_t ofs = (size_t)(row0 + cr0 + j) * 128 + colg;
            float ag = aggf[(cr0 + j) * 128 + ccol * 8 + (h * 4 + cc)];
            msg[ofs] = msg[ofs] + ag + fmaxf(o[cc][j] + b2, 0.f);
        }
    }
}

// ---------------- initial message (K=160, pad 147) ----------------
__launch_bounds__(256, 3)
__global__ void imsg_k(const float* __restrict__ af, const float* __restrict__ ef,
                       const int* __restrict__ idx_j,
                       const short* __restrict__ Wt, const float* __restrict__ bias,
                       float* __restrict__ msg) {
    __shared__ short lds[64 * 256];
    const int tid = threadIdx.x;
    const int lane = tid & 63, w = tid >> 6;
    const int row0 = blockIdx.x * 64;

    #pragma unroll
    for (int it = 0; it < 5; ++it) {
        int chunk = tid + it * 256;
        int r = chunk / 20, cg = chunk % 20;
        int row = row0 + r;
        int g = idx_j[row];
        unsigned u[4];
        #pragma unroll
        for (int h = 0; h < 4; ++h) {
            int k0 = cg * 8 + 2 * h;
            int k1 = k0 + 1;
            float f0 = (k0 < 133) ? af[(size_t)g * 133 + k0]
                     : (k0 < 147) ? ef[(size_t)row * 14 + (k0 - 133)] : 0.f;
            float f1 = (k1 < 133) ? af[(size_t)g * 133 + k1]
                     : (k1 < 147) ? ef[(size_t)row * 14 + (k1 - 133)] : 0.f;
            u[h] = pack2(f0, f1);
        }
        *(uint4*)&lds[sidxg(r, cg * 16, 256)] = make_uint4(u[0], u[1], u[2], u[3]);
    }
    __syncthreads();

    const int kgrp = lane >> 4, ccol = lane & 15;
    const int arow = w * 16 + ccol;
    const int cr0  = w * 16 + kgrp * 4;
    short8 a[5];
    #pragma unroll
    for (int kb = 0; kb < 5; ++kb)
        a[kb] = *(const short8*)&lds[sidxg(arow, kb * 64 + kgrp * 16, 256)];
    floatx4 o[8];
    colmm8_pf<5, 160>(a, Wt + ccol * 160 + kgrp * 8, o);
    #pragma unroll
    for (int c = 0; c < 8; ++c) {
        int colg = c * 16 + ccol;
        float bv = bias[colg];
        #pragma unroll
        for (int j = 0; j < 4; ++j)
            msg[(size_t)(row0 + cr0 + j) * 128 + colg] = fmaxf(o[c][j] + bv, 0.f);
    }
}

// ---------------- layerA (streaming weights) ----------------
__launch_bounds__(256, 3)
__global__ void layerA_k(const float* __restrict__ msg, const short* __restrict__ rbfe,
                         const short* __restrict__ kjWt, const float* __restrict__ kjB,
                         const short* __restrict__ rbf2Wt, const float* __restrict__ rbf2B,
                         const short* __restrict__ downWt, const float* __restrict__ downB,
                         short* __restrict__ xdown) {
    __shared__ short ldsM[64 * 128];
    __shared__ short ldsR[64 * 128];
    const int tid = threadIdx.x;
    const int lane = tid & 63, w = tid >> 6;
    const size_t row0 = (size_t)blockIdx.x * 64;
    stage64x128(msg, row0, ldsM, tid);
    stage_bf(rbfe, row0, ldsR, tid);
    __syncthreads();
    const int kgrp = lane >> 4, ccol = lane & 15;
    const int arow = w * 16 + ccol;
    const int cr0  = w * 16 + kgrp * 4;
    short8 aM[4], aR[4];
    #pragma unroll
    for (int kb = 0; kb < 4; ++kb) {
        aM[kb] = *(const short8*)&ldsM[sidx(arow, kb * 64 + kgrp * 16)];
        aR[kb] = *(const short8*)&ldsR[sidx(arow, kb * 64 + kgrp * 16)];
    }
    floatx4 oR[8], oK[8];
    colmm8_pf<4, 128>(aR, rbf2Wt + ccol * 128 + kgrp * 8, oR);
    colmm8_pf<4, 128>(aM, kjWt   + ccol * 128 + kgrp * 8, oK);
    #pragma unroll
    for (int c = 0; c < 8; ++c) {
        int colg = c * 16 + ccol;
        float rb = rbf2B[colg], kbb = kjB[colg];
        #pragma unroll
        for (int j = 0; j < 4; ++j) {
            float x = fmaxf(oK[c][j] + kbb, 0.f) * fmaxf(oR[c][j] + rb, 0.f);
            ldsM[sidx(cr0 + j, 2 * colg)] = f2bf(x);
        }
    }
    short8 aX[4];
    #pragma unroll
    for (int kb = 0; kb < 4; ++kb)
        aX[kb] = *(const short8*)&ldsM[sidx(arow, kb * 64 + kgrp * 16)];
    colmm8_pf<4, 128>(aX, downWt + ccol * 128 + kgrp * 8, oK);
    #pragma unroll
    for (int j = 0; j < 4; ++j) {
        short8 v;
        #pragma unroll
        for (int c = 0; c < 8; ++c)
            v[c] = f2bf(fmaxf(oK[c][j] + downB[c * 16 + ccol], 0.f));
        *(short8*)&xdown[(row0 + cr0 + j) * 128 + ccol * 8] = v;
    }
}

// ---------------- rbfe FUSED (rbf_h K=32 stage + K=128 GEMM, bf16 out) ----------------
__launch_bounds__(256, 3)
__global__ void rbfe_k(const float* __restrict__ rbf0, const short* __restrict__ W16,
                       const float* __restrict__ b16, const short* __restrict__ W3t,
                       const float* __restrict__ bias,
                       const int* __restrict__ idx_i, const int* __restrict__ idx_j,
                       const int* __restrict__ atype,
                       const float* __restrict__ P1, const float* __restrict__ P2,
                       short* __restrict__ out) {
    __shared__ short lds[64 * 128];
    const int tid = threadIdx.x;
    const int lane = tid & 63, w = tid >> 6;
    const int row0 = blockIdx.x * 64;
    const int kgrp = lane >> 4, ccol = lane & 15;
    const int arow = w * 16 + ccol;
    const int cr0  = w * 16 + kgrp * 4;

    {
        short8 a0;
        if (kgrp < 2) {
            int grow = row0 + arow;
            float4 r0 = *(const float4*)&rbf0[(size_t)grow * 16 + kgrp * 8];
            float4 r1 = *(const float4*)&rbf0[(size_t)grow * 16 + kgrp * 8 + 4];
            a0[0] = f2bf(r0.x); a0[1] = f2bf(r0.y); a0[2] = f2bf(r0.z); a0[3] = f2bf(r0.w);
            a0[4] = f2bf(r1.x); a0[5] = f2bf(r1.y); a0[6] = f2bf(r1.z); a0[7] = f2bf(r1.w);
        } else {
            a0 = short8{0, 0, 0, 0, 0, 0, 0, 0};
        }
        floatx4 o[8];
        colmm8_pf<1, 32>(&a0, W16 + ccol * 32 + kgrp * 8, o);
        #pragma unroll
        for (int c = 0; c < 8; ++c) {
            float bv = b16[c * 16 + ccol];
            #pragma unroll
            for (int j = 0; j < 4; ++j)
                lds[sidx(cr0 + j, 2 * (c * 16 + ccol))] = f2bf(fmaxf(o[c][j] + bv, 0.f));
        }
    }
    // band-local -> no barrier

    const float* p1p[4]; const float* p2p[4];
    #pragma unroll
    for (int j = 0; j < 4; ++j) {
        int row = row0 + cr0 + j;
        p1p[j] = P1 + (size_t)atype[idx_i[row]] * 128;
        p2p[j] = P2 + (size_t)atype[idx_j[row]] * 128;
    }
    short8 a[4];
    #pragma unroll
    for (int kb = 0; kb < 4; ++kb)
        a[kb] = *(const short8*)&lds[sidx(arow, kb * 64 + kgrp * 16)];
    floatx4 o[8];
    colmm8_pf<4, 128>(a, W3t + ccol * 128 + kgrp * 8, o);
    #pragma unroll
    for (int c = 0; c < 8; ++c) {
        int colg = c * 16 + ccol;
        float bv = bias[colg];
        #pragma unroll
        for (int j = 0; j < 4; ++j)
            out[(size_t)(row0 + cr0 + j) * 128 + colg] =
                f2bf(fmaxf(o[c][j] + bv + p1p[j][colg] + p2p[j][colg], 0.f));
    }
}

// ---------------- final projection: one-hot folded, K=161 fp32, col-half split ----------------
// out = relu(T[atype] + af[:,100:133] @ W[100:133] + atomm @ W[133:261])
// W row index = 100 + kg uniformly (kg 0..160).
__launch_bounds__(256)
__global__ void final_k(const float* __restrict__ af, const float* __restrict__ atomm,
                        const int* __restrict__ atype, const float* __restrict__ T,
                        const float* __restrict__ W, float* __restrict__ Y) {
    __shared__ float xs[96 * 68];
    const int tid = threadIdx.x;
    const int row0 = (blockIdx.x >> 1) * 64;
    const int hc = (blockIdx.x & 1) * 64;
    const int col4 = (tid & 15) * 4;
    const int r0 = (tid >> 4) * 4;

    float acc[4][4];
    #pragma unroll
    for (int r = 0; r < 4; ++r) {
        int row = row0 + r0 + r;
        if (row < Ncnt) {
            float4 tv = *(const float4*)&T[(size_t)atype[row] * 128 + hc + col4];
            acc[r][0] = tv.x; acc[r][1] = tv.y; acc[r][2] = tv.z; acc[r][3] = tv.w;
        } else {
            acc[r][0] = acc[r][1] = acc[r][2] = acc[r][3] = 0.f;
        }
    }

    for (int kb = 0; kb < 161; kb += 96) {
        int kc = (161 - kb < 96) ? (161 - kb) : 96;
        __syncthreads();
        for (int idx = tid; idx < 64 * 96; idx += 256) {
            int r = idx / 96, kl = idx % 96;
            if (kl < kc) {
                int row = row0 + r;
                float v = 0.f;
                if (row < Ncnt) {
                    int kg = kb + kl;
                    v = (kg < 33) ? af[(size_t)row * 133 + 100 + kg]
                                  : atomm[(size_t)row * 128 + (kg - 33)];
                }
                xs[kl * 68 + r] = v;
            }
        }
        __syncthreads();
        for (int k = 0; k < kc; ++k) {
            float4 xv = *(const float4*)&xs[k * 68 + r0];
            float4 wv = *(const float4*)&W[(size_t)(100 + kb + k) * 128 + hc + col4];
            float xr[4] = {xv.x, xv.y, xv.z, xv.w};
            float wc[4] = {wv.x, wv.y, wv.z, wv.w};
            #pragma unroll
            for (int r = 0; r < 4; ++r)
                #pragma unroll
                for (int c = 0; c < 4; ++c)
                    acc[r][c] = fmaf(xr[r], wc[c], acc[r][c]);
        }
    }

    #pragma unroll
    for (int r = 0; r < 4; ++r) {
        int row = row0 + r0 + r;
        if (row >= Ncnt) continue;
        float4 o = make_float4(fmaxf(acc[r][0], 0.f), fmaxf(acc[r][1], 0.f),
                               fmaxf(acc[r][2], 0.f), fmaxf(acc[r][3], 0.f));
        *(float4*)&Y[(size_t)row * 128 + hc + col4] = o;
    }
}

// ---------------- host ----------------

extern "C" void kernel_launch(void* const* d_in, const int* in_sizes, int n_in,
                              void* d_out, int out_size, void* d_ws, size_t ws_size,
                              hipStream_t stream) {
    const float* atom_feature = (const float*)d_in[0];
    const float* edge_feature = (const float*)d_in[1];
    const float* dist         = (const float*)d_in[2];
    const float* angle        = (const float*)d_in[3];
    const float* W_i1_w       = (const float*)d_in[4];
    const float* W_i1_b       = (const float*)d_in[5];
    const float* emb_table    = (const float*)d_in[6];
    const float* lin_rbf_w    = (const float*)d_in[7];
    const float* lin_rbf_b    = (const float*)d_in[8];
    const float* lin_emb_w    = (const float*)d_in[9];
    const float* lin_emb_b    = (const float*)d_in[10];
    const float* bessel_freq  = (const float*)d_in[11];
    const float* L_rbf2_w     = (const float*)d_in[12];
    const float* L_rbf2_b     = (const float*)d_in[13];
    const float* L_kj_w       = (const float*)d_in[14];
    const float* L_kj_b       = (const float*)d_in[15];
    const float* L_sbf1_w     = (const float*)d_in[16];
    const float* L_sbf2_w     = (const float*)d_in[17];
    const float* L_down_w     = (const float*)d_in[18];
    const float* L_down_b     = (const float*)d_in[19];
    const float* L_up_w       = (const float*)d_in[20];
    const float* L_up_b       = (const float*)d_in[21];
    const float* L_res1_w     = (const float*)d_in[22];
    const float* L_res1_b     = (const float*)d_in[23];
    const float* L_res2_w     = (const float*)d_in[24];
    const float* L_res2_b     = (const float*)d_in[25];
    const float* W_o_w        = (const float*)d_in[26];
    const float* W_o_b        = (const float*)d_in[27];
    const int* idx_i          = (const int*)d_in[28];
    const int* idx_j          = (const int*)d_in[29];
    const int* idx_kj         = (const int*)d_in[30];
    const int* ib_eid         = (const int*)d_in[32];
    const int* ib_atom        = (const int*)d_in[33];

    float* ws = (float*)d_ws;
    size_t off = 0;
    auto take = [&](size_t n) { float* p = ws + off; off += n; return p; };
    float* msg    = take((size_t)Ecnt * 128);
    short* rbfe   = (short*)take((size_t)Ecnt * 64);
    short* sxd    = (short*)take((size_t)Ecnt * 64);
    short* ysort  = (short*)take((size_t)Tcnt * 64);
    float* rbf0b  = take((size_t)Ecnt * 16);
    float* P1     = take(100 * 128);
    float* P2     = take(100 * 128);
    float* Tbl    = take(100 * 128);
    int*   atyp   = (int*)take(Ncnt);
    int*   cnts   = (int*)take(Ecnt);
    int*   sstart = (int*)take(Ecnt + 1);
    int*   cur    = (int*)take(Ecnt);
    int*   btot   = (int*)take(512);
    int*   boff   = (int*)take(512);
    int*   eids   = (int*)take(Tcnt);
    float* angs   = take(Tcnt);
    int*   sstartA= (int*)take(Ncnt + 1);
    int*   eidsA  = (int*)take(Ecnt);
    short* wts    = (short*)take(160100);

    if (off * sizeof(float) > ws_size) {
        sentinel_k<<<1, 256, 0, stream>>>((float*)d_out, (float)ws_size);
        return;
    }

    float* atomm = (float*)ysort;   // alias: ysort dead after last layerBf

    const int GE  = Ecnt / 64;
    const int NBE = (Ecnt + 255) / 256;
    const int NBT = (Tcnt + 255) / 256;
    const int NBA = (Ncnt + 255) / 256;

    atype_k<<<(Ncnt + 255) / 256, 256, 0, stream>>>(atom_feature, atyp);
    pemb_k<<<100, 128, 0, stream>>>(emb_table, lin_emb_w, P1, P2);
    rbf0_k<<<NBE, 256, 0, stream>>>(dist, bessel_freq, rbf0b);
    tprep_k<<<50, 256, 0, stream>>>(W_o_w, W_o_b, Tbl);

    // --- edge CSR sort (triplets by target edge) ---
    hipMemsetAsync(cnts, 0, (size_t)Ecnt * sizeof(int), stream);
    hist_k<<<NBT, 256, 0, stream>>>(idx_kj, cnts, Tcnt);
    scan1_k<<<NBE, 256, 0, stream>>>(cnts, btot, Ecnt);
    scan2_k<<<1, 512, 0, stream>>>(btot, boff, NBE);
    scan3_k<<<NBE, 256, 0, stream>>>(cnts, boff, sstart, cur, Ecnt, Tcnt);
    perm_k<<<NBT, 256, 0, stream>>>(idx_kj, angle, cur, eids, angs);

    // --- atom CSR sort (incoming edges by atom) ---
    hipMemsetAsync(cnts, 0, (size_t)Ncnt * sizeof(int), stream);
    hist_k<<<NBE, 256, 0, stream>>>(ib_atom, cnts, Ecnt);
    scan1_k<<<NBA, 256, 0, stream>>>(cnts, btot, Ncnt);
    scan2_k<<<1, 512, 0, stream>>>(btot, boff, NBA);
    scan3_k<<<NBA, 256, 0, stream>>>(cnts, boff, sstartA, cur, Ncnt, Ecnt);
    permA_k<<<NBE, 256, 0, stream>>>(ib_atom, ib_eid, cur, eidsA);

    // --- weight prep ---
    short* p = wts;
    short* wt1[2]; short* wt2[2]; short* wt3[2];
    short* wkj[2]; short* wr2f[2]; short* wdn[2]; short* wr1[2]; short* wr2[2];
    for (int l = 0; l < 2; ++l) {
        wt1[l] = p; p += 96 * 128;
        wt2[l] = p; p += 128 * 128;
        wt3[l] = p; p += 128 * 128;
        wkj[l] = p; p += 128 * 128;
        wr2f[l] = p; p += 128 * 128;
        wdn[l] = p; p += 128 * 128;
        wr1[l] = p; p += 128 * 128;
        wr2[l] = p; p += 128 * 128;
    }
    short* wemb3 = p; p += 128 * 128;
    short* wi1t  = p; p += 128 * 160;
    short* w16   = p; p += 128 * 32;

    WPack wp;
    int m = 0;
    for (int l = 0; l < 2; ++l) {
        wp.src[m] = L_kj_w   + (size_t)l * 128 * 128; wp.dst[m] = wkj[l];  wp.perm[m++] = 0;
        wp.src[m] = L_rbf2_w + (size_t)l * 128 * 128; wp.dst[m] = wr2f[l]; wp.perm[m++] = 0;
        wp.src[m] = L_down_w + (size_t)l * 128 * 128; wp.dst[m] = wdn[l];  wp.perm[m++] = 0;
        wp.src[m] = L_res1_w + (size_t)l * 128 * 128; wp.dst[m] = wr1[l];  wp.perm[m++] = 1;
        wp.src[m] = L_res2_w + (size_t)l * 128 * 128; wp.dst[m] = wr2[l];  wp.perm[m++] = 0;
    }
    wp.src[m] = lin_emb_w + 256 * 128; wp.dst[m] = wemb3; wp.perm[m++] = 0;   // 11
    transmany_k<<<11 * 64, 256, 0, stream>>>(wp);

    FPack fp;
    m = 0;
    for (int l = 0; l < 2; ++l) {
        fp.src[m] = L_sbf1_w + (size_t)l * 96 * 128;  fp.dst[m] = wt1[l]; fp.nkb[m++] = 3;
        fp.src[m] = L_sbf2_w + (size_t)l * 128 * 128; fp.dst[m] = wt2[l]; fp.nkb[m++] = 4;
        fp.src[m] = L_up_w   + (size_t)l * 128 * 128; fp.dst[m] = wt3[l]; fp.nkb[m++] = 4;
    }
    transfragall_k<<<6 * 64, 256, 0, stream>>>(fp);
    transWi1_k<<<(128 * 160 + 255) / 256, 256, 0, stream>>>(W_i1_w, wi1t);
    transW16_k<<<16, 256, 0, stream>>>(lin_rbf_w, w16);

    // --- initial message + fused rbf_e ---
    imsg_k<<<GE, 256, 0, stream>>>(atom_feature, edge_feature, idx_j, wi1t, W_i1_b, msg);
    rbfe_k<<<GE, 256, 0, stream>>>(rbf0b, w16, lin_rbf_b, wemb3, lin_emb_b,
                                   idx_i, idx_j, atyp, P1, P2, rbfe);

    for (int l = 0; l < 2; ++l) {
        layerA_k<<<GE, 256, 0, stream>>>(msg, rbfe,
                                         wkj[l], L_kj_b + (size_t)l * 128,
                                         wr2f[l], L_rbf2_b + (size_t)l * 128,
                                         wdn[l], L_down_b + (size_t)l * 128, sxd);
        triplet_mfma_k<<<512, 512, 0, stream>>>(angs, eids, rbf0b,
                                                wt1[l], wt2[l], wt3[l],
                                                L_up_b + (size_t)l * 128, sxd, ysort);
        layerBf_k<<<GE, 512, 0, stream>>>(ysort, sstart,
                                          wr1[l], L_res1_b + (size_t)l * 128,
                                          wr2[l], L_res2_b + (size_t)l * 128, msg);
    }

    // atom aggregation (CSR, no atomics) + final projection (one-hot folded)
    atomsum_k<<<(Ncnt * 128) / 256, 256, 0, stream>>>(msg, eidsA, sstartA, atomm);
    final_k<<<((Ncnt + 63) / 64) * 2, 256, 0, stream>>>(atom_feature, atomm, atyp,
                                                        Tbl, W_o_w, (float*)d_out);
}